// Round 16
// baseline (606.005 us; speedup 1.0000x reference)
//
#include <hip/hip_runtime.h>
#include <cstddef>
#include <cstdint>

#define NN 1024
#define BB 16
#define NKNOTS 11

typedef __attribute__((ext_vector_type(8))) short short8_v;
typedef __attribute__((ext_vector_type(4))) float f32x4;
typedef __attribute__((ext_vector_type(8))) unsigned short ushort8_v;
typedef __attribute__((ext_vector_type(4))) unsigned short ushort4_v;
typedef __attribute__((ext_vector_type(4))) unsigned int uint4_v;
typedef __attribute__((ext_vector_type(2))) unsigned int uint2_v;

// ---- workspace byte offsets ----
#define WPK_OFF   ((size_t)0)                         // 1024x1024 bf16 = 2MB
#define M3_OFF    ((size_t)2 << 20)                   // 1024x128 u32 = 512KB
#define STHI_OFF  ((size_t)6 << 20)                   // 4 x 1M ushort = 8MB
#define STLO_OFF  ((size_t)14 << 20)                  // 8MB
#define WGT_OFF   ((size_t)22 << 20)                  // 16KB bf16 linear W^T
#define SYNC_OFF  (((size_t)22 << 20) + 16384)        // 16 batches x 32 u32
#define LOSS_OFF  (SYNC_OFF + 2048)
#define Z_OFF     (LOSS_OFF + 256)
#define DINV_OFF  (Z_OFF + 4096)

// ---- scan kernel LDS layout (bytes) ----
// GEMM: 3 bufs x 24576 @ 0/24576/49152; buf = [B0 8K][B1 8K][B2 8K],
//   rows 128B = 8 chunks of 16B, data chunk c stored at c^(row&7).
// Epilogue overlay (bufs dead after GEMM loop):
#define AGGS   0        // f32 [32][68]
#define AGGH   8704     // bf16 plane [32 i][64 c], row 128B, chunk^=(row&7)
#define AGGL   12800
#define HH_    16896    // bf16 plane [32 i][64 c] of h_k
#define HL_    20992
#define HT32   25088    // packed hi/lo u32 plane [64 c][32 i], row 128B
#define REDS   33280    // reg-head partials (1KB)
#define PL1    35328    // pred layer1 (4KB)
#define LUT_OFF 73728   // persistent: 16 x 8B nibble->short4 mask LUT

__device__ __forceinline__ unsigned short f2bf(float x) {
  unsigned int u = __float_as_uint(x);
  return (unsigned short)((u + 0x7FFFu + ((u >> 16) & 1u)) >> 16);
}
__device__ __forceinline__ float bf2f(unsigned short h) {
  return __uint_as_float(((unsigned int)h) << 16);
}
__device__ __forceinline__ void gload16(const void* g, void* l) {
  __builtin_amdgcn_global_load_lds(
      (const __attribute__((address_space(1))) unsigned int*)g,
      (__attribute__((address_space(3))) unsigned int*)l, 16, 0, 0);
}

// -------------------------------------------------------------------------
// Kernel 1: per-row softmax denominator Z[j] and degree rsqrt dinv[j]
// -------------------------------------------------------------------------
__global__ __launch_bounds__(256) void rowstats_kernel(
    const float* __restrict__ emb, const float* __restrict__ A,
    float* __restrict__ Z, float* __restrict__ dinv)
{
  const int j = blockIdx.x;
  const int tid = threadIdx.x;
  __shared__ float ej[64];
  __shared__ float r1[256], r2[256];
  if (tid < 64) ej[tid] = emb[j * 64 + tid];
  __syncthreads();
  float zs = 0.f, as = 0.f;
  for (int i = tid; i < NN; i += 256) {
    const float4* er = (const float4*)(emb + (size_t)i * 64);
    float dot = 0.f;
#pragma unroll
    for (int q = 0; q < 16; ++q) {
      float4 e = er[q];
      dot += e.x * ej[q * 4 + 0] + e.y * ej[q * 4 + 1] +
             e.z * ej[q * 4 + 2] + e.w * ej[q * 4 + 3];
    }
    zs += expf(fmaxf(dot, 0.f));
    as += A[(size_t)j * NN + i];
  }
  r1[tid] = zs; r2[tid] = as;
  __syncthreads();
  for (int s = 128; s > 0; s >>= 1) {
    if (tid < s) { r1[tid] += r1[tid + s]; r2[tid] += r2[tid + s]; }
    __syncthreads();
  }
  if (tid == 0) {
    Z[j] = r1[0];
    dinv[j] = rsqrtf(r2[0] + 1.0f);
  }
}

// -------------------------------------------------------------------------
// Kernel 2 (v3): build packed W (bf16, unmasked) + per-octet bin masks M3.
// -------------------------------------------------------------------------
__global__ __launch_bounds__(256) void build_wt_kernel(
    const float* __restrict__ emb, const float* __restrict__ A,
    const float* __restrict__ delay, const float* __restrict__ Z,
    const float* __restrict__ dinv,
    unsigned short* __restrict__ Wpk, unsigned int* __restrict__ M3g)
{
  __shared__ float eI[64][65];
  __shared__ float eJ[64][65];
  __shared__ float wS[64][65];     // [jj][ii]
  __shared__ unsigned char dS[64][64];
  __shared__ float diS[64];

  const int tid = threadIdx.x;
  const int it = blockIdx.x >> 4, jt = blockIdx.x & 15;
  const int i0 = it * 64, j0 = jt * 64;

  for (int q = tid; q < 4096; q += 256) {
    int r = q >> 6, c = q & 63;
    eI[r][c] = emb[(size_t)(i0 + r) * 64 + c];
    eJ[r][c] = emb[(size_t)(j0 + r) * 64 + c];
  }
  if (tid < 64) diS[tid] = dinv[i0 + tid];
  __syncthreads();

  const int jj = tid >> 2, iig = (tid & 3) * 16;
  float dotv[16];
#pragma unroll
  for (int m = 0; m < 16; ++m) dotv[m] = 0.f;
#pragma unroll 4
  for (int h4 = 0; h4 < 16; ++h4) {
    float4 a = *(const float4*)&eJ[jj][h4 * 4];
#pragma unroll
    for (int m = 0; m < 16; ++m) {
      float4 bb = *(const float4*)&eI[iig + m][h4 * 4];
      dotv[m] += a.x * bb.x + a.y * bb.y + a.z * bb.z + a.w * bb.w;
    }
  }
  const float Zj = Z[j0 + jj], dj = dinv[j0 + jj];
  const float* Ap = A + (size_t)(j0 + jj) * NN + i0 + iig;
  const float* Dp = delay + (size_t)(j0 + jj) * NN + i0 + iig;
#pragma unroll
  for (int m = 0; m < 16; ++m) {
    float aji = Ap[m] + ((i0 + iig + m) == (j0 + jj) ? 1.f : 0.f);
    float ac = expf(fmaxf(dotv[m], 0.f)) / Zj + dj * diS[iig + m] * aji;
    float w = (ac > 0.001f) ? ac : 0.f;
    float dl = fminf(fmaxf(Dp[m], 0.f), 2.f);
    wS[jj][iig + m] = w;
    dS[jj][iig + m] = (unsigned char)(int)rintf(dl);
  }
  __syncthreads();

  const int iw = tid >> 2, jg = (tid & 3) * 16;
  ushort8_v P0, P1;
#pragma unroll
  for (int m = 0; m < 8; ++m) {
    P0[m] = f2bf(wS[jg + m][iw]);
    P1[m] = f2bf(wS[jg + 8 + m][iw]);
  }
  size_t woff = (size_t)(i0 + iw) * NN + j0 + jg;
  *(ushort8_v*)(Wpk + woff) = P0;
  *(ushort8_v*)(Wpk + woff + 8) = P1;
  uint2_v mw;
#pragma unroll
  for (int o = 0; o < 2; ++o) {
    unsigned int m0 = 0, m1 = 0, m2 = 0;
#pragma unroll
    for (int e = 0; e < 8; ++e) {
      int dv = dS[jg + o * 8 + e][iw];
      m0 |= (dv == 0) << e;
      m1 |= (dv == 1) << e;
      m2 |= (dv == 2) << e;
    }
    mw[o] = m0 | (m1 << 8) | (m2 << 16);
  }
  *(uint2_v*)(M3g + (size_t)(i0 + iw) * 128 + (j0 + jg) / 8) = mw;
}

// -------------------------------------------------------------------------
// Kernel 3 (v2): init S slices 0,1; blocks 256..287 build linear W^T (wgt).
// -------------------------------------------------------------------------
__global__ __launch_bounds__(256) void init_s_kernel(
    const float* __restrict__ ca, const float* __restrict__ W1,
    const float* __restrict__ b1, const float* __restrict__ W2,
    const float* __restrict__ b2,
    unsigned short* __restrict__ SThi, unsigned short* __restrict__ STlo,
    const float* __restrict__ Wm, const float* __restrict__ Wsm,
    unsigned short* __restrict__ wgt)
{
  const int bid = blockIdx.x;
  const int tid = threadIdx.x;
  if (bid >= 256) {   // wgt: [n][kk] linear
    int e = (bid - 256) * 256 + tid;
    int n = e >> 7, kk = e & 127;
    float v = (kk < 64) ? Wm[kk * 64 + n] : Wsm[(kk - 64) * 64 + n];
    wgt[n * 128 + kk] = f2bf(v);
    return;
  }
  __shared__ float l1S[64][65];
  __shared__ float W2S[64][128];
  __shared__ float hidS[64][129];

  const int nt = bid >> 4, b = bid & 15;
  const int n0 = nt * 64;

  for (int q = tid; q < 2048; q += 256)
    ((float4*)&W2S[0][0])[q] = ((const float4*)W2)[q];

  {
    const int n = tid >> 2, hb = (tid & 3) * 16;
    float2 x = *(const float2*)(ca + ((size_t)(b * NN + n0 + n) * NKNOTS) * 2);
#pragma unroll
    for (int m = 0; m < 16; ++m) {
      int h = hb + m;
      l1S[n][h] = fmaxf(x.x * W1[h] + x.y * W1[64 + h] + b1[h], 0.f);
    }
  }
  __syncthreads();
  {
    const int nn = tid & 63, o0 = (tid >> 6) * 32;
    float hid[32];
#pragma unroll
    for (int o = 0; o < 32; ++o) hid[o] = b2[o0 + o];
    for (int h = 0; h < 64; ++h) {
      float lv = l1S[nn][h];
#pragma unroll
      for (int o = 0; o < 32; ++o) hid[o] = fmaf(lv, W2S[h][o0 + o], hid[o]);
    }
#pragma unroll
    for (int o = 0; o < 32; ++o) hidS[nn][o0 + o] = hid[o];
  }
  __syncthreads();
  {
    const int r = tid >> 1, hf = tid & 1;
    const int t = r >> 6, hh = r & 63;
    size_t off = ((size_t)t << 20) + (size_t)(b * 64 + hh) * NN + n0 + hf * 32;
    ushort8_v H[4], L[4];
#pragma unroll
    for (int q = 0; q < 4; ++q)
#pragma unroll
      for (int m = 0; m < 8; ++m) {
        float v = hidS[hf * 32 + q * 8 + m][r];
        unsigned short hv = f2bf(v);
        H[q][m] = hv; L[q][m] = f2bf(v - bf2f(hv));
      }
#pragma unroll
    for (int q = 0; q < 4; ++q) {
      *(ushort8_v*)(SThi + off + q * 8) = H[q];
      *(ushort8_v*)(STlo + off + q * 8) = L[q];
    }
  }
}

// -------------------------------------------------------------------------
// Kernel 4: FUSED persistent scan, M=32 tiles, 2 blocks/CU.
//   Grid 512 = 32 i_t x 16 b; bid%8 == b%8 (batch pinned to XCD).
//   B staged in LDS (3 bufs x 24KB); W + masks stream global->register;
//   wgt read from global (L1-hot). Co-resident independent blocks
//   overlap each other's stalls.
// -------------------------------------------------------------------------
__global__ __launch_bounds__(512, 4) void scan_kernel(
    const unsigned short* __restrict__ Wpk, const unsigned int* __restrict__ M3g,
    unsigned short* __restrict__ SThi, unsigned short* __restrict__ STlo,
    const unsigned short* __restrict__ wgt, unsigned int* __restrict__ syncc,
    const float* __restrict__ Wx, const float* __restrict__ db,
    const float* __restrict__ cb, const float* __restrict__ cc,
    const float* __restrict__ cd, const float* __restrict__ ca,
    const float* __restrict__ rW1, const float* __restrict__ rb1,
    const float* __restrict__ rW2, const float* __restrict__ rb2,
    const float* __restrict__ pW1, const float* __restrict__ pb1,
    const float* __restrict__ pW2, const float* __restrict__ pb2,
    float* __restrict__ out, float* __restrict__ loss)
{
  __shared__ __align__(16) char smem[73856];
  __shared__ float sWx[128];
  __shared__ float sdb[64];

  const int tid  = threadIdx.x;
  const int lane = tid & 63;
  const int w    = tid >> 6;            // wave 0..7
  const int bid  = blockIdx.x;
  const int i_t = bid >> 4;             // 0..31
  const int b   = bid & 15;             // batch (bid%8 == b%8 -> XCD pin)
  const int i0 = i_t * 32, c0 = b * 64;

  // GEMM wave map: fr = w&1 (row frag), wc = (w>>1)&1, kh = w>>2
  const int fr = w & 1, wc = (w >> 1) & 1, kh = w >> 2;
  const int g = lane >> 4, l15 = lane & 15;

  if (tid < 128) sWx[tid] = Wx[tid];
  else if (tid < 192) sdb[tid - 128] = db[tid - 128];

  // nibble->short4 mask LUT (16 x 8B), persistent
  if (tid < 32) {
    int n = tid >> 1, half = tid & 1;
    unsigned int dw = half == 0
      ? (((n & 1) ? 0xFFFFu : 0u) | ((n & 2) ? 0xFFFF0000u : 0u))
      : (((n & 4) ? 0xFFFFu : 0u) | ((n & 8) ? 0xFFFF0000u : 0u));
    *(unsigned int*)(smem + LUT_OFF + n * 8 + half * 4) = dw;
  }
  __syncthreads();

  // staging map (B only): row = tid>>3 (0..63 c-rows), ch = tid&7
  const int s_row = tid >> 3;
  const int s_ch  = tid & 7;
  const int s_cx  = (s_ch ^ (s_row & 7)) * 8;
  // fragment offsets
  const int koff = kh * 4 + g;                        // k-chunk 0..7
  const int s16  = (koff ^ (l15 & 7)) << 4;
  const int rB0  = (wc * 32 + l15) * 128 + s16;
  // W/mask global row pointers (per-lane)
  const unsigned short* Wrow = Wpk + (size_t)(i0 + fr * 16 + l15) * NN + koff * 8;
  const unsigned int*   Mrow = M3g + (size_t)(i0 + fr * 16 + l15) * 128 + koff;

  float (*aggS)[68] = (float (*)[68])(smem + AGGS);

  for (int k = 0; k < 12; ++k) {
    f32x4 acc[2];
    acc[0] = (f32x4){0.f, 0.f, 0.f, 0.f};
    acc[1] = (f32x4){0.f, 0.f, 0.f, 0.f};

    auto stage = [&](int t) {   // 3 gload16/thread (one per bin's B slice)
      const int jc = t << 6;
      char* dst = smem + (t % 3) * 24576;
#pragma unroll
      for (int d = 0; d < 3; ++d) {
        int td = k + 1 - d; if (td < 0) td = 0;
        gload16(SThi + ((size_t)(td & 3) << 20) +
                    (size_t)(c0 + s_row) * NN + jc + s_cx,
                dst + d * 8192 + tid * 16);
      }
    };

    short8_v wv_c, wv_n;
    unsigned int wm_c, wm_n;
    wv_c = *(const short8_v*)(Wrow);
    wm_c = Mrow[0];
    stage(0); stage(1);
    asm volatile("s_waitcnt vmcnt(3)" ::: "memory");   // wv_c + stage(0) done
    __builtin_amdgcn_s_barrier();

    for (int t = 0; t < 16; ++t) {
      if (t < 15) {
        wv_n = *(const short8_v*)(Wrow + (t + 1) * 64);
        wm_n = Mrow[(t + 1) * 8];
      }
      if (t < 14) stage(t + 2);
      const char* bp = smem + (t % 3) * 24576;
#pragma unroll
      for (int d = 0; d < 3; ++d) {
        unsigned int mb = (wm_c >> (8 * d)) & 0xFF;
        uint2_v lo = *(const uint2_v*)(smem + LUT_OFF + (mb & 15) * 8);
        uint2_v hi = *(const uint2_v*)(smem + LUT_OFF + (mb >> 4) * 8);
        short8_v a = wv_c;
        unsigned int* ap = (unsigned int*)&a;
        ap[0] &= lo[0]; ap[1] &= lo[1]; ap[2] &= hi[0]; ap[3] &= hi[1];
        short8_v b0 = *(const short8_v*)(bp + d * 8192 + rB0);
        short8_v b1 = *(const short8_v*)(bp + d * 8192 + rB0 + 2048);
        acc[0] = __builtin_amdgcn_mfma_f32_16x16x32_bf16(a, b0, acc[0], 0, 0, 0);
        acc[1] = __builtin_amdgcn_mfma_f32_16x16x32_bf16(a, b1, acc[1], 0, 0, 0);
      }
      __builtin_amdgcn_sched_barrier(0);
      if (t < 14) {
        asm volatile("s_waitcnt vmcnt(3)" ::: "memory");  // t+1 fully ready
        __builtin_amdgcn_s_barrier();
      } else if (t == 14) {
        asm volatile("s_waitcnt vmcnt(0)" ::: "memory");
        __builtin_amdgcn_s_barrier();
      }
      wv_c = wv_n; wm_c = wm_n;
    }
    __syncthreads();   // buf reads done; LDS reusable

    // ---- merge kh halves into aggS (fp32) ----
    if (kh == 0) {
#pragma unroll
      for (int fc = 0; fc < 2; ++fc)
#pragma unroll
        for (int rr = 0; rr < 4; ++rr)
          aggS[fr * 16 + g * 4 + rr][wc * 32 + fc * 16 + l15] = acc[fc][rr];
    }
    __syncthreads();
    if (kh == 1) {
#pragma unroll
      for (int fc = 0; fc < 2; ++fc)
#pragma unroll
        for (int rr = 0; rr < 4; ++rr)
          aggS[fr * 16 + g * 4 + rr][wc * 32 + fc * 16 + l15] += acc[fc][rr];
    }
    __syncthreads();

    // ---- planes: tid<256 agg->bf16 hi/lo; tid>=256 stage h_k ----
    if (tid < 256) {
      const int row = tid >> 3, c8 = tid & 7;
      const float* src = &aggS[row][c8 * 8];
      ushort8_v H, L;
#pragma unroll
      for (int q = 0; q < 8; ++q) {
        float f = src[q];
        unsigned short hv = f2bf(f);
        H[q] = hv; L[q] = f2bf(f - bf2f(hv));
      }
      const int pos = (c8 ^ (row & 7)) << 4;
      *(ushort8_v*)(smem + AGGH + row * 128 + pos) = H;
      *(ushort8_v*)(smem + AGGL + row * 128 + pos) = L;
    } else {
      const int t2 = tid - 256;
      const int cl = t2 >> 2, ich = (t2 & 3) * 8;   // 64 c x 8 i each
      size_t off = ((size_t)((k + 1) & 3) << 20) + (size_t)(c0 + cl) * NN + (i0 + ich);
      ushort8_v h8 = *(const ushort8_v*)(SThi + off);
      ushort8_v l8 = *(const ushort8_v*)(STlo + off);
#pragma unroll
      for (int q = 0; q < 8; ++q) {
        int i = ich + q;
        int byo = i * 128 + ((((cl >> 3) ^ (i & 7))) << 4) + (cl & 7) * 2;
        *(unsigned short*)(smem + HH_ + byo) = h8[q];
        *(unsigned short*)(smem + HL_ + byo) = l8[q];
      }
    }
    __syncthreads();

    // ---- MFMA mini-GEMM: pre = [agg|h](32x128) @ wgt (128x64) ----
    const int mr = w & 1, nc = w >> 1;   // 2 row-frags x 4 col-frags
    f32x4 pacc = (f32x4){0.f, 0.f, 0.f, 0.f};
#pragma unroll
    for (int ks = 0; ks < 4; ++ks) {
      const int base = (ks < 2) ? AGGH : HH_;
      const int cxa = (((ks & 1) * 4 + g) ^ (l15 & 7)) << 4;
      const char* ra = smem + base + (mr * 16 + l15) * 128 + cxa;
      short8_v aH = *(const short8_v*)ra;
      short8_v aL = *(const short8_v*)(ra + 4096);
      short8_v bv = *(const short8_v*)(wgt + (size_t)(nc * 16 + l15) * 128 + (ks * 4 + g) * 8);
      pacc = __builtin_amdgcn_mfma_f32_16x16x32_bf16(aH, bv, pacc, 0, 0, 0);
      pacc = __builtin_amdgcn_mfma_f32_16x16x32_bf16(aL, bv, pacc, 0, 0, 0);
    }
    __syncthreads();   // plane reads done before HT32 overlay writes

    // ---- dx@Wx + bias, tanh; write ST ring + packed hT32 plane ----
    const int ksp = (k < 11) ? k : 10;
    float hn[4];
    const int hcol = nc * 16 + l15;
#pragma unroll
    for (int rr = 0; rr < 4; ++rr) {
      int iG = i0 + mr * 16 + g * 4 + rr;
      size_t cbase = ((size_t)(b * NN + iG) * NKNOTS + ksp) * 2;
      float dx0 = cb[cbase + 0], dx1 = cb[cbase + 1];
      if (k == 11) {   // frac = 1: der = b + 2c + 3d
        dx0 += 2.f * cc[cbase + 0] + 3.f * cd[cbase + 0];
        dx1 += 2.f * cc[cbase + 1] + 3.f * cd[cbase + 1];
      }
      float pre = pacc[rr] + dx0 * sWx[hcol] + dx1 * sWx[64 + hcol] + sdb[hcol];
      hn[rr] = tanhf(pre);
    }
    {
      int iG0 = i0 + mr * 16 + g * 4;
      size_t off2 = ((size_t)((k + 2) & 3) << 20) + (size_t)(c0 + hcol) * NN + iG0;
      ushort4_v H4, L4;
      uint4_v pk;
#pragma unroll
      for (int rr = 0; rr < 4; ++rr) {
        unsigned short hv = f2bf(hn[rr]);
        unsigned short lv = f2bf(hn[rr] - bf2f(hv));
        H4[rr] = hv; L4[rr] = lv;
        pk[rr] = ((unsigned int)hv << 16) | lv;
      }
      *(ushort4_v*)(SThi + off2) = H4;
      *(ushort4_v*)(STlo + off2) = L4;
      const int ci = mr * 4 + g;           // i-chunk 0..7
      *(uint4_v*)(smem + HT32 + hcol * 128 + ((ci ^ (hcol & 7)) << 4)) = pk;
    }
    // ---- signal-early: ST stores L2-visible after vmcnt(0) drain ----
    asm volatile("s_waitcnt vmcnt(0)" ::: "memory");
    __syncthreads();
    if (tid == 0) atomicAdd(&syncc[b * 32 + k], 1u);

    // ---- reg head + Huber (h_new from hT32 plane; 8 groups x 32 rows) ----
    {
      float* redS = (float*)(smem + REDS);
      if (tid < 256) {
        const int ii = tid & 31, mg4 = (tid >> 5) * 4;   // mg4 0..28
        float s0 = rb1[mg4], s1 = rb1[mg4 + 1], s2 = rb1[mg4 + 2], s3 = rb1[mg4 + 3];
#pragma unroll 8
        for (int h = 0; h < 64; ++h) {
          unsigned int v = *(const unsigned int*)(smem + HT32 + h * 128 +
                             ((((ii >> 2) ^ (h & 7))) << 4) + (ii & 3) * 4);
          float f = bf2f((unsigned short)(v >> 16)) + bf2f((unsigned short)(v & 0xffff));
          float4 wv = *(const float4*)(rW1 + h * 32 + mg4);
          s0 = fmaf(f, wv.x, s0); s1 = fmaf(f, wv.y, s1);
          s2 = fmaf(f, wv.z, s2); s3 = fmaf(f, wv.w, s3);
        }
        float4 r2v = *(const float4*)(rW2 + mg4);
        float rp = fmaxf(s0, 0.f) * r2v.x + fmaxf(s1, 0.f) * r2v.y +
                   fmaxf(s2, 0.f) * r2v.z + fmaxf(s3, 0.f) * r2v.w;
        redS[(tid >> 5) * 32 + ii] = rp;
      }
      __syncthreads();
      if (tid < 32) {
        float rv = rb2[0];
#pragma unroll
        for (int m = 0; m < 8; ++m) rv += redS[m * 32 + tid];
        int iG = i0 + tid;
        size_t tb = ((size_t)(b * NN + iG) * NKNOTS + ksp) * 2;
        float tgt = ca[tb];
        if (k == 11) tgt += cb[tb] + cc[tb] + cd[tb];   // frac=1: a+b+c+d
        float dv = rv - tgt;
        float ad = fabsf(dv);
        float hub = (ad < 1.f) ? 0.5f * dv * dv : (ad - 0.5f);
        hub += __shfl_down(hub, 16);
        hub += __shfl_down(hub, 8);
        hub += __shfl_down(hub, 4);
        hub += __shfl_down(hub, 2);
        hub += __shfl_down(hub, 1);
        if (tid == 0) atomicAdd(loss, hub);
      }
    }

    // ---- pred head (k == 11 only; 8 groups x 32 rows) ----
    if (k == 11) {
      __syncthreads();
      if (tid < 256) {
        const int ii = tid & 31, mg4 = (tid >> 5) * 4;   // mg4 0..28
        float s0 = pb1[mg4], s1 = pb1[mg4 + 1], s2 = pb1[mg4 + 2], s3 = pb1[mg4 + 3];
#pragma unroll 8
        for (int h = 0; h < 64; ++h) {
          unsigned int v = *(const unsigned int*)(smem + HT32 + h * 128 +
                             ((((ii >> 2) ^ (h & 7))) << 4) + (ii & 3) * 4);
          float f = bf2f((unsigned short)(v >> 16)) + bf2f((unsigned short)(v & 0xffff));
          float4 wv = *(const float4*)(pW1 + h * 32 + mg4);
          s0 = fmaf(f, wv.x, s0); s1 = fmaf(f, wv.y, s1);
          s2 = fmaf(f, wv.z, s2); s3 = fmaf(f, wv.w, s3);
        }
        float* pl1 = (float*)(smem + PL1);
        pl1[ii * 32 + mg4 + 0] = fmaxf(s0, 0.f);
        pl1[ii * 32 + mg4 + 1] = fmaxf(s1, 0.f);
        pl1[ii * 32 + mg4 + 2] = fmaxf(s2, 0.f);
        pl1[ii * 32 + mg4 + 3] = fmaxf(s3, 0.f);
      }
      __syncthreads();
      if (tid < 384) {   // 32 rows x 12 outs
        float* pl1 = (float*)(smem + PL1);
        int i_ = tid / 12, o = tid % 12;
        float s = pb2[o];
#pragma unroll
        for (int m = 0; m < 32; ++m) s = fmaf(pl1[i_ * 32 + m], pW2[m * 12 + o], s);
        out[((size_t)b * NN + (i0 + i_)) * 12 + o] = s;
      }
    }

    // ---- per-batch wait (32 arrivals, XCD-local) + L1-only invalidate ----
    __syncthreads();
    if (tid == 0) {
      unsigned int* ctr = &syncc[b * 32 + k];
      while (atomicAdd(ctr, 0u) < 32u) __builtin_amdgcn_s_sleep(1);
      asm volatile("buffer_inv sc0" ::: "memory");   // drop stale vector-L1
    }
    __syncthreads();
  }
}

__global__ void finalize_kernel(const float* __restrict__ loss, float* __restrict__ out)
{
  out[196608] = loss[0] * (1.0f / 196608.0f);
}

// -------------------------------------------------------------------------
extern "C" void kernel_launch(void* const* d_in, const int* in_sizes, int n_in,
                              void* d_out, int out_size, void* d_ws, size_t ws_size,
                              hipStream_t stream)
{
  const float* A     = (const float*)d_in[0];
  const float* delay = (const float*)d_in[1];
  const float* ca    = (const float*)d_in[2];
  const float* cb    = (const float*)d_in[3];
  const float* cc    = (const float*)d_in[4];
  const float* cd    = (const float*)d_in[5];
  const float* emb   = (const float*)d_in[6];
  const float* iW1   = (const float*)d_in[7];
  const float* ib1   = (const float*)d_in[8];
  const float* iW2   = (const float*)d_in[9];
  const float* ib2   = (const float*)d_in[10];
  const float* Wm    = (const float*)d_in[11];
  const float* Wsm   = (const float*)d_in[12];
  const float* Wx    = (const float*)d_in[13];
  const float* db    = (const float*)d_in[14];
  const float* rW1   = (const float*)d_in[15];
  const float* rb1   = (const float*)d_in[16];
  const float* rW2   = (const float*)d_in[17];
  const float* rb2   = (const float*)d_in[18];
  const float* pW1   = (const float*)d_in[19];
  const float* pb1   = (const float*)d_in[20];
  const float* pW2   = (const float*)d_in[21];
  const float* pb2   = (const float*)d_in[22];

  char* wsb = (char*)d_ws;
  float* out = (float*)d_out;
  unsigned short* Wpk  = (unsigned short*)(wsb + WPK_OFF);
  unsigned int*  M3g   = (unsigned int*)(wsb + M3_OFF);
  unsigned short* SThi = (unsigned short*)(wsb + STHI_OFF);
  unsigned short* STlo = (unsigned short*)(wsb + STLO_OFF);
  unsigned short* wgt  = (unsigned short*)(wsb + WGT_OFF);
  unsigned int* syncc  = (unsigned int*)(wsb + SYNC_OFF);
  float* loss          = (float*)(wsb + LOSS_OFF);
  float* Z             = (float*)(wsb + Z_OFF);
  float* dinv          = (float*)(wsb + DINV_OFF);

  hipMemsetAsync(syncc, 0, 2048 + 64, stream);   // sync counters + loss
  rowstats_kernel<<<NN, 256, 0, stream>>>(emb, A, Z, dinv);
  build_wt_kernel<<<256, 256, 0, stream>>>(emb, A, delay, Z, dinv, Wpk, M3g);
  init_s_kernel<<<288, 256, 0, stream>>>(ca, iW1, ib1, iW2, ib2,
                                         SThi, STlo, Wm, Wsm, wgt);
  scan_kernel<<<512, 512, 0, stream>>>(
      Wpk, M3g, SThi, STlo, wgt, syncc, Wx, db, cb, cc, cd, ca,
      rW1, rb1, rW2, rb2, pW1, pb1, pW2, pb2, out, loss);
  finalize_kernel<<<1, 1, 0, stream>>>(loss, out);
}

// Round 17
// 389.067 us; speedup vs baseline: 1.5576x; 1.5576x over previous
//
#include <hip/hip_runtime.h>
#include <cstddef>
#include <cstdint>

#define NN 1024
#define BB 16
#define NKNOTS 11

typedef __attribute__((ext_vector_type(8))) short short8_v;
typedef __attribute__((ext_vector_type(4))) float f32x4;
typedef __attribute__((ext_vector_type(8))) unsigned short ushort8_v;
typedef __attribute__((ext_vector_type(4))) unsigned short ushort4_v;
typedef __attribute__((ext_vector_type(4))) unsigned int uint4_v;
typedef __attribute__((ext_vector_type(2))) unsigned int uint2_v;

// ---- workspace byte offsets ----
#define WPK_OFF   ((size_t)0)                         // 1024x1024 bf16 = 2MB
#define M3_OFF    ((size_t)2 << 20)                   // 1024x128 u32 = 512KB
#define STHI_OFF  ((size_t)6 << 20)                   // 4 x 1M ushort = 8MB
#define STLO_OFF  ((size_t)14 << 20)                  // 8MB
#define WGT_OFF   ((size_t)22 << 20)                  // 16KB bf16 swizzled W^T
#define SYNC_OFF  (((size_t)22 << 20) + 16384)        // 16 batches x 32 u32
#define LOSS_OFF  (SYNC_OFF + 2048)
#define Z_OFF     (LOSS_OFF + 256)
#define DINV_OFF  (Z_OFF + 4096)

// ---- scan kernel LDS layout (bytes) ----
// GEMM: 4 bufs x 34816 @ 0/34816/69632/104448.
//   buf = [W 8K][M3 2K][B0 8K][B1 8K][B2 8K]; rows 128B = 8 chunks of 16B,
//   data chunk c stored at c^(row&7). M3: [64 rows][8 octs] u32 linear.
// Epilogue overlay (bufs dead after GEMM loop):
#define AGGS   0        // f32 [64][68]
#define AGGH   17408    // bf16 plane [64 i][64 c], row 128B, chunk^=(row&7)
#define AGGL   25600
#define HH_    33792    // bf16 plane [64 i][64 c] of h_k
#define HL_    41984
#define HT32   50176    // packed hi/lo u32 plane [64 c][64 i]
#define REDS   66560    // reg-head partials (2KB)
#define PL1    68608    // pred layer1 (8KB)
#define WGT_L  139264   // persistent: swizzled W^T bf16 (16KB)
#define LUT_OFF 155648  // persistent: 16 x 8B nibble->short4 mask LUT

__device__ __forceinline__ unsigned short f2bf(float x) {
  unsigned int u = __float_as_uint(x);
  return (unsigned short)((u + 0x7FFFu + ((u >> 16) & 1u)) >> 16);
}
__device__ __forceinline__ float bf2f(unsigned short h) {
  return __uint_as_float(((unsigned int)h) << 16);
}
__device__ __forceinline__ void gload16(const void* g, void* l) {
  __builtin_amdgcn_global_load_lds(
      (const __attribute__((address_space(1))) unsigned int*)g,
      (__attribute__((address_space(3))) unsigned int*)l, 16, 0, 0);
}
__device__ __forceinline__ void gload4(const void* g, void* l) {
  __builtin_amdgcn_global_load_lds(
      (const __attribute__((address_space(1))) unsigned int*)g,
      (__attribute__((address_space(3))) unsigned int*)l, 4, 0, 0);
}

// -------------------------------------------------------------------------
// Kernel 1: per-row softmax denominator Z[j] and degree rsqrt dinv[j]
// -------------------------------------------------------------------------
__global__ __launch_bounds__(256) void rowstats_kernel(
    const float* __restrict__ emb, const float* __restrict__ A,
    float* __restrict__ Z, float* __restrict__ dinv)
{
  const int j = blockIdx.x;
  const int tid = threadIdx.x;
  __shared__ float ej[64];
  __shared__ float r1[256], r2[256];
  if (tid < 64) ej[tid] = emb[j * 64 + tid];
  __syncthreads();
  float zs = 0.f, as = 0.f;
  for (int i = tid; i < NN; i += 256) {
    const float4* er = (const float4*)(emb + (size_t)i * 64);
    float dot = 0.f;
#pragma unroll
    for (int q = 0; q < 16; ++q) {
      float4 e = er[q];
      dot += e.x * ej[q * 4 + 0] + e.y * ej[q * 4 + 1] +
             e.z * ej[q * 4 + 2] + e.w * ej[q * 4 + 3];
    }
    zs += expf(fmaxf(dot, 0.f));
    as += A[(size_t)j * NN + i];
  }
  r1[tid] = zs; r2[tid] = as;
  __syncthreads();
  for (int s = 128; s > 0; s >>= 1) {
    if (tid < s) { r1[tid] += r1[tid + s]; r2[tid] += r2[tid + s]; }
    __syncthreads();
  }
  if (tid == 0) {
    Z[j] = r1[0];
    dinv[j] = rsqrtf(r2[0] + 1.0f);
  }
}

// -------------------------------------------------------------------------
// Kernel 2 (v3): build packed W (bf16, unmasked) + per-octet bin masks M3.
// -------------------------------------------------------------------------
__global__ __launch_bounds__(256) void build_wt_kernel(
    const float* __restrict__ emb, const float* __restrict__ A,
    const float* __restrict__ delay, const float* __restrict__ Z,
    const float* __restrict__ dinv,
    unsigned short* __restrict__ Wpk, unsigned int* __restrict__ M3g)
{
  __shared__ float eI[64][65];
  __shared__ float eJ[64][65];
  __shared__ float wS[64][65];     // [jj][ii]
  __shared__ unsigned char dS[64][64];
  __shared__ float diS[64];

  const int tid = threadIdx.x;
  const int it = blockIdx.x >> 4, jt = blockIdx.x & 15;
  const int i0 = it * 64, j0 = jt * 64;

  for (int q = tid; q < 4096; q += 256) {
    int r = q >> 6, c = q & 63;
    eI[r][c] = emb[(size_t)(i0 + r) * 64 + c];
    eJ[r][c] = emb[(size_t)(j0 + r) * 64 + c];
  }
  if (tid < 64) diS[tid] = dinv[i0 + tid];
  __syncthreads();

  const int jj = tid >> 2, iig = (tid & 3) * 16;
  float dotv[16];
#pragma unroll
  for (int m = 0; m < 16; ++m) dotv[m] = 0.f;
#pragma unroll 4
  for (int h4 = 0; h4 < 16; ++h4) {
    float4 a = *(const float4*)&eJ[jj][h4 * 4];
#pragma unroll
    for (int m = 0; m < 16; ++m) {
      float4 bb = *(const float4*)&eI[iig + m][h4 * 4];
      dotv[m] += a.x * bb.x + a.y * bb.y + a.z * bb.z + a.w * bb.w;
    }
  }
  const float Zj = Z[j0 + jj], dj = dinv[j0 + jj];
  const float* Ap = A + (size_t)(j0 + jj) * NN + i0 + iig;
  const float* Dp = delay + (size_t)(j0 + jj) * NN + i0 + iig;
#pragma unroll
  for (int m = 0; m < 16; ++m) {
    float aji = Ap[m] + ((i0 + iig + m) == (j0 + jj) ? 1.f : 0.f);
    float ac = expf(fmaxf(dotv[m], 0.f)) / Zj + dj * diS[iig + m] * aji;
    float w = (ac > 0.001f) ? ac : 0.f;
    float dl = fminf(fmaxf(Dp[m], 0.f), 2.f);
    wS[jj][iig + m] = w;
    dS[jj][iig + m] = (unsigned char)(int)rintf(dl);
  }
  __syncthreads();

  const int iw = tid >> 2, jg = (tid & 3) * 16;
  ushort8_v P0, P1;
#pragma unroll
  for (int m = 0; m < 8; ++m) {
    P0[m] = f2bf(wS[jg + m][iw]);
    P1[m] = f2bf(wS[jg + 8 + m][iw]);
  }
  size_t woff = (size_t)(i0 + iw) * NN + j0 + jg;
  *(ushort8_v*)(Wpk + woff) = P0;
  *(ushort8_v*)(Wpk + woff + 8) = P1;
  uint2_v mw;
#pragma unroll
  for (int o = 0; o < 2; ++o) {
    unsigned int m0 = 0, m1 = 0, m2 = 0;
#pragma unroll
    for (int e = 0; e < 8; ++e) {
      int dv = dS[jg + o * 8 + e][iw];
      m0 |= (dv == 0) << e;
      m1 |= (dv == 1) << e;
      m2 |= (dv == 2) << e;
    }
    mw[o] = m0 | (m1 << 8) | (m2 << 16);
  }
  *(uint2_v*)(M3g + (size_t)(i0 + iw) * 128 + (j0 + jg) / 8) = mw;
}

// -------------------------------------------------------------------------
// Kernel 3 (v2): init S slices 0,1; blocks 256..287 build swizzled W^T.
// -------------------------------------------------------------------------
__global__ __launch_bounds__(256) void init_s_kernel(
    const float* __restrict__ ca, const float* __restrict__ W1,
    const float* __restrict__ b1, const float* __restrict__ W2,
    const float* __restrict__ b2,
    unsigned short* __restrict__ SThi, unsigned short* __restrict__ STlo,
    const float* __restrict__ Wm, const float* __restrict__ Wsm,
    unsigned short* __restrict__ wgt)
{
  const int bid = blockIdx.x;
  const int tid = threadIdx.x;
  if (bid >= 256) {   // wgt part (chunk-swizzled per n)
    int e = (bid - 256) * 256 + tid;
    int n = e >> 7, kk = e & 127;
    float v = (kk < 64) ? Wm[kk * 64 + n] : Wsm[(kk - 64) * 64 + n];
    wgt[n * 128 + (((kk >> 3) ^ (n & 15)) << 3) + (kk & 7)] = f2bf(v);
    return;
  }
  __shared__ float l1S[64][65];
  __shared__ float W2S[64][128];
  __shared__ float hidS[64][129];

  const int nt = bid >> 4, b = bid & 15;
  const int n0 = nt * 64;

  for (int q = tid; q < 2048; q += 256)
    ((float4*)&W2S[0][0])[q] = ((const float4*)W2)[q];

  {
    const int n = tid >> 2, hb = (tid & 3) * 16;
    float2 x = *(const float2*)(ca + ((size_t)(b * NN + n0 + n) * NKNOTS) * 2);
#pragma unroll
    for (int m = 0; m < 16; ++m) {
      int h = hb + m;
      l1S[n][h] = fmaxf(x.x * W1[h] + x.y * W1[64 + h] + b1[h], 0.f);
    }
  }
  __syncthreads();
  {
    const int nn = tid & 63, o0 = (tid >> 6) * 32;
    float hid[32];
#pragma unroll
    for (int o = 0; o < 32; ++o) hid[o] = b2[o0 + o];
    for (int h = 0; h < 64; ++h) {
      float lv = l1S[nn][h];
#pragma unroll
      for (int o = 0; o < 32; ++o) hid[o] = fmaf(lv, W2S[h][o0 + o], hid[o]);
    }
#pragma unroll
    for (int o = 0; o < 32; ++o) hidS[nn][o0 + o] = hid[o];
  }
  __syncthreads();
  {
    const int r = tid >> 1, hf = tid & 1;
    const int t = r >> 6, hh = r & 63;
    size_t off = ((size_t)t << 20) + (size_t)(b * 64 + hh) * NN + n0 + hf * 32;
    ushort8_v H[4], L[4];
#pragma unroll
    for (int q = 0; q < 4; ++q)
#pragma unroll
      for (int m = 0; m < 8; ++m) {
        float v = hidS[hf * 32 + q * 8 + m][r];
        unsigned short hv = f2bf(v);
        H[q][m] = hv; L[q][m] = f2bf(v - bf2f(hv));
      }
#pragma unroll
    for (int q = 0; q < 4; ++q) {
      *(ushort8_v*)(SThi + off + q * 8) = H[q];
      *(ushort8_v*)(STlo + off + q * 8) = L[q];
    }
  }
}

// -------------------------------------------------------------------------
// Kernel 4: FUSED persistent scan (round-14 structure), batch-local sync,
//   PACKED-W GEMM with 4-buffer 3-deep counted-vmcnt pipeline + setprio.
// -------------------------------------------------------------------------
__global__ __launch_bounds__(512, 2) void scan_kernel(
    const unsigned short* __restrict__ Wpk, const unsigned int* __restrict__ M3g,
    unsigned short* __restrict__ SThi, unsigned short* __restrict__ STlo,
    const unsigned short* __restrict__ wgt, unsigned int* __restrict__ syncc,
    const float* __restrict__ Wx, const float* __restrict__ db,
    const float* __restrict__ cb, const float* __restrict__ cc,
    const float* __restrict__ cd, const float* __restrict__ ca,
    const float* __restrict__ rW1, const float* __restrict__ rb1,
    const float* __restrict__ rW2, const float* __restrict__ rb2,
    const float* __restrict__ pW1, const float* __restrict__ pb1,
    const float* __restrict__ pW2, const float* __restrict__ pb2,
    float* __restrict__ out, float* __restrict__ loss)
{
  __shared__ __align__(16) char smem[155776];
  __shared__ float sWx[128];
  __shared__ float sdb[64];

  const int tid  = threadIdx.x;
  const int lane = tid & 63;
  const int w    = tid >> 6;            // wave 0..7
  const int bid  = blockIdx.x;
  // batch-local decode: bid%8 == b%8 -> batch pinned to one XCD
  const int i_t = bid >> 4;             // 0..15
  const int b   = bid & 15;             // batch
  const int i0 = i_t * 64, c0 = b * 64;

  const int wr = (w >> 1) & 1, wc = w & 1, kh = w >> 2;
  const int g = lane >> 4, l15 = lane & 15;

  if (tid < 128) sWx[tid] = Wx[tid];
  else if (tid < 192) sdb[tid - 128] = db[tid - 128];

  // nibble->short4 mask LUT (16 x 8B), persistent
  if (tid < 32) {
    int n = tid >> 1, half = tid & 1;
    unsigned int dw = half == 0
      ? (((n & 1) ? 0xFFFFu : 0u) | ((n & 2) ? 0xFFFF0000u : 0u))
      : (((n & 4) ? 0xFFFFu : 0u) | ((n & 8) ? 0xFFFF0000u : 0u));
    *(unsigned int*)(smem + LUT_OFF + n * 8 + half * 4) = dw;
  }

  // stage swizzled W^T bf16 (16KB) once, persistent @WGT_L
  gload16(wgt + (size_t)tid * 8,        smem + WGT_L + tid * 16);
  gload16(wgt + 4096 + (size_t)tid * 8, smem + WGT_L + 8192 + tid * 16);
  __syncthreads();   // drains wgt gloads; LUT visible

  // staging map: row = tid>>3 (0..63), ch = tid&7
  const int s_row = tid >> 3;
  const int s_ch  = tid & 7;
  const int s_cx  = (s_ch ^ (s_row & 7)) * 8;
  // fragment byte offsets
  const int koff  = kh * 4 + g;                       // chunk/oct index 0..7
  const int s16   = (koff ^ (l15 & 7)) << 4;
  const int rowA0 = wr * 32 + l15;
  const int rB0   = 10240 + (wc * 32 + l15) * 128 + s16;

  float (*aggS)[68] = (float (*)[68])(smem + AGGS);

  for (int k = 0; k < 12; ++k) {
    // ===== GEMM: 16 j-chunk iters, 3 bins/iter via mask-AND, 3-deep =====
    f32x4 acc[2][2];
#pragma unroll
    for (int fr = 0; fr < 2; ++fr)
#pragma unroll
      for (int fc = 0; fc < 2; ++fc)
        acc[fr][fc] = (f32x4){0.f, 0.f, 0.f, 0.f};

    auto stage = [&](int t) {   // t = j-chunk 0..15; 5 loads/thread
      const int jc = t << 6;
      char* dst = smem + (t & 3) * 34816;
      gload16(Wpk + (size_t)(i0 + s_row) * NN + jc + s_cx, dst + tid * 16);
      gload4(M3g + (size_t)(i0 + s_row) * 128 + (jc >> 3) + s_ch,
             dst + 8192 + tid * 4);
#pragma unroll
      for (int d = 0; d < 3; ++d) {
        int td = k + 1 - d; if (td < 0) td = 0;
        gload16(SThi + ((size_t)(td & 3) << 20) +
                    (size_t)(c0 + s_row) * NN + jc + s_cx,
                dst + 10240 + d * 8192 + tid * 16);
      }
    };

    stage(0); stage(1); stage(2);
    asm volatile("s_waitcnt vmcnt(10)" ::: "memory");   // stage(0) landed
    __builtin_amdgcn_s_barrier();

    for (int t = 0; t < 16; ++t) {
      if (t < 13) stage(t + 3);
      const char* bp = smem + (t & 3) * 34816;
      // W fragments + mask words
      short8_v w0 = *(const short8_v*)(bp + rowA0 * 128 + s16);
      short8_v w1 = *(const short8_v*)(bp + (rowA0 + 16) * 128 + s16);
      unsigned int m0 = *(const unsigned int*)(bp + 8192 + rowA0 * 32 + koff * 4);
      unsigned int m1 = *(const unsigned int*)(bp + 8192 + (rowA0 + 16) * 32 + koff * 4);
      __builtin_amdgcn_s_setprio(1);
#pragma unroll
      for (int d = 0; d < 3; ++d) {
        unsigned int mb0 = (m0 >> (8 * d)) & 0xFF;
        unsigned int mb1 = (m1 >> (8 * d)) & 0xFF;
        uint2_v lo0 = *(const uint2_v*)(smem + LUT_OFF + (mb0 & 15) * 8);
        uint2_v hi0 = *(const uint2_v*)(smem + LUT_OFF + (mb0 >> 4) * 8);
        uint2_v lo1 = *(const uint2_v*)(smem + LUT_OFF + (mb1 & 15) * 8);
        uint2_v hi1 = *(const uint2_v*)(smem + LUT_OFF + (mb1 >> 4) * 8);
        short8_v a0 = w0, a1 = w1;
        unsigned int* a0p = (unsigned int*)&a0;
        unsigned int* a1p = (unsigned int*)&a1;
        a0p[0] &= lo0[0]; a0p[1] &= lo0[1]; a0p[2] &= hi0[0]; a0p[3] &= hi0[1];
        a1p[0] &= lo1[0]; a1p[1] &= lo1[1]; a1p[2] &= hi1[0]; a1p[3] &= hi1[1];
        short8_v b0 = *(const short8_v*)(bp + d * 8192 + rB0);
        short8_v b1 = *(const short8_v*)(bp + d * 8192 + rB0 + 16 * 128);
        acc[0][0] = __builtin_amdgcn_mfma_f32_16x16x32_bf16(a0, b0, acc[0][0], 0, 0, 0);
        acc[0][1] = __builtin_amdgcn_mfma_f32_16x16x32_bf16(a0, b1, acc[0][1], 0, 0, 0);
        acc[1][0] = __builtin_amdgcn_mfma_f32_16x16x32_bf16(a1, b0, acc[1][0], 0, 0, 0);
        acc[1][1] = __builtin_amdgcn_mfma_f32_16x16x32_bf16(a1, b1, acc[1][1], 0, 0, 0);
      }
      __builtin_amdgcn_s_setprio(0);
      __builtin_amdgcn_sched_barrier(0);
      if (t < 13) {
        asm volatile("s_waitcnt vmcnt(10)" ::: "memory");  // buf t+1 ready
        __builtin_amdgcn_s_barrier();
      } else if (t == 13) {
        asm volatile("s_waitcnt vmcnt(5)" ::: "memory");
        __builtin_amdgcn_s_barrier();
      } else if (t == 14) {
        asm volatile("s_waitcnt vmcnt(0)" ::: "memory");
        __builtin_amdgcn_s_barrier();
      }
    }
    __syncthreads();   // last buf reads done; LDS reusable

    // ---- merge kh halves into aggS (fp32) ----
    if (kh == 0) {
#pragma unroll
      for (int fr = 0; fr < 2; ++fr)
#pragma unroll
        for (int fc = 0; fc < 2; ++fc)
#pragma unroll
          for (int rr = 0; rr < 4; ++rr)
            aggS[wr * 32 + fr * 16 + g * 4 + rr][wc * 32 + fc * 16 + l15] = acc[fr][fc][rr];
    }
    __syncthreads();
    if (kh == 1) {
#pragma unroll
      for (int fr = 0; fr < 2; ++fr)
#pragma unroll
        for (int fc = 0; fc < 2; ++fc)
#pragma unroll
          for (int rr = 0; rr < 4; ++rr)
            aggS[wr * 32 + fr * 16 + g * 4 + rr][wc * 32 + fc * 16 + l15] += acc[fr][fc][rr];
    }
    __syncthreads();

    // ---- aggS -> bf16 hi/lo planes (chunk-swizzled) ----
    {
      const int row = tid >> 3, c8 = tid & 7;
      const float* src = &aggS[row][c8 * 8];
      ushort8_v H, L;
#pragma unroll
      for (int q = 0; q < 8; ++q) {
        float f = src[q];
        unsigned short hv = f2bf(f);
        H[q] = hv; L[q] = f2bf(f - bf2f(hv));
      }
      const int pos = (c8 ^ (row & 7)) << 4;
      *(ushort8_v*)(smem + AGGH + row * 128 + pos) = H;
      *(ushort8_v*)(smem + AGGL + row * 128 + pos) = L;
    }
    // ---- stage h_k -> hH/hL planes ----
    {
      const int cl = tid >> 3, ich = (tid & 7) * 8;
      size_t off = ((size_t)((k + 1) & 3) << 20) + (size_t)(c0 + cl) * NN + (i0 + ich);
      ushort8_v h8 = *(const ushort8_v*)(SThi + off);
      ushort8_v l8 = *(const ushort8_v*)(STlo + off);
#pragma unroll
      for (int q = 0; q < 8; ++q) {
        int i = ich + q;
        int byo = i * 128 + ((((cl >> 3) ^ (i & 7))) << 4) + (cl & 7) * 2;
        *(unsigned short*)(smem + HH_ + byo) = h8[q];
        *(unsigned short*)(smem + HL_ + byo) = l8[q];
      }
    }
    __syncthreads();

    // ---- MFMA mini-GEMM: pre = [agg|h](64x128) @ W^T-frags (K=128) ----
    const int mr = w & 3, nc = w >> 2;   // 4 row-frags x 2 col-pairs
    f32x4 pacc[2];
    pacc[0] = (f32x4){0.f, 0.f, 0.f, 0.f};
    pacc[1] = (f32x4){0.f, 0.f, 0.f, 0.f};
#pragma unroll
    for (int ks = 0; ks < 4; ++ks) {
      const int base = (ks < 2) ? AGGH : HH_;
      const int ks2 = ks & 1;
      const int cxa = ((ks2 * 4 + g) ^ (l15 & 7)) << 4;
      const char* ra = smem + base + (mr * 16 + l15) * 128 + cxa;
      short8_v aH = *(const short8_v*)ra;
      short8_v aL = *(const short8_v*)(ra + 8192);
#pragma unroll
      for (int fc = 0; fc < 2; ++fc) {
        const int n = (nc * 2 + fc) * 16 + l15;
        const int cxb = ((ks * 4 + g) ^ l15) << 4;
        short8_v bv = *(const short8_v*)(smem + WGT_L + n * 256 + cxb);
        pacc[fc] = __builtin_amdgcn_mfma_f32_16x16x32_bf16(aH, bv, pacc[fc], 0, 0, 0);
        pacc[fc] = __builtin_amdgcn_mfma_f32_16x16x32_bf16(aL, bv, pacc[fc], 0, 0, 0);
      }
    }
    __syncthreads();   // plane reads done before HT32 overlay writes

    // ---- dx@Wx + bias, tanh; write ST ring + packed hT32 plane ----
    const int ksp = (k < 11) ? k : 10;
    float hn[2][4];
#pragma unroll
    for (int rr = 0; rr < 4; ++rr) {
      int iG = i0 + mr * 16 + g * 4 + rr;
      size_t cbase = ((size_t)(b * NN + iG) * NKNOTS + ksp) * 2;
      float dx0 = cb[cbase + 0], dx1 = cb[cbase + 1];
      if (k == 11) {   // frac = 1: der = b + 2c + 3d
        dx0 += 2.f * cc[cbase + 0] + 3.f * cd[cbase + 0];
        dx1 += 2.f * cc[cbase + 1] + 3.f * cd[cbase + 1];
      }
#pragma unroll
      for (int fc = 0; fc < 2; ++fc) {
        int hcol = (nc * 2 + fc) * 16 + l15;
        float pre = pacc[fc][rr] + dx0 * sWx[hcol] + dx1 * sWx[64 + hcol] + sdb[hcol];
        hn[fc][rr] = tanhf(pre);
      }
    }
#pragma unroll
    for (int fc = 0; fc < 2; ++fc) {
      int hcol = (nc * 2 + fc) * 16 + l15;
      int iG0 = i0 + mr * 16 + g * 4;
      size_t off2 = ((size_t)((k + 2) & 3) << 20) + (size_t)(c0 + hcol) * NN + iG0;
      ushort4_v H4, L4;
      uint4_v pk;
#pragma unroll
      for (int rr = 0; rr < 4; ++rr) {
        unsigned short hv = f2bf(hn[fc][rr]);
        unsigned short lv = f2bf(hn[fc][rr] - bf2f(hv));
        H4[rr] = hv; L4[rr] = lv;
        pk[rr] = ((unsigned int)hv << 16) | lv;
      }
      *(ushort4_v*)(SThi + off2) = H4;
      *(ushort4_v*)(STlo + off2) = L4;
      const int ci = mr * 4 + g;           // i-chunk (4 i's = 16B)
      *(uint4_v*)(smem + HT32 + hcol * 256 + ((ci ^ (hcol & 15)) << 4)) = pk;
    }
    // ---- signal-early: ST stores are L2-visible after vmcnt(0) drain ----
    asm volatile("s_waitcnt vmcnt(0)" ::: "memory");
    __syncthreads();                        // all threads' stores drained
    if (tid == 0) atomicAdd(&syncc[b * 32 + k], 1u);

    // ---- reg head + Huber (h_new from hT32 plane) ----
    {
      const int ii = tid & 63, mg4 = (tid >> 6) * 4;
      float s0 = rb1[mg4], s1 = rb1[mg4 + 1], s2 = rb1[mg4 + 2], s3 = rb1[mg4 + 3];
#pragma unroll 8
      for (int h = 0; h < 64; ++h) {
        unsigned int v = *(const unsigned int*)(smem + HT32 + h * 256 +
                           ((((ii >> 2) ^ (h & 15))) << 4) + (ii & 3) * 4);
        float f = bf2f((unsigned short)(v >> 16)) + bf2f((unsigned short)(v & 0xffff));
        float4 wv = *(const float4*)(rW1 + h * 32 + mg4);
        s0 = fmaf(f, wv.x, s0); s1 = fmaf(f, wv.y, s1);
        s2 = fmaf(f, wv.z, s2); s3 = fmaf(f, wv.w, s3);
      }
      float4 r2v = *(const float4*)(rW2 + mg4);
      float rp = fmaxf(s0, 0.f) * r2v.x + fmaxf(s1, 0.f) * r2v.y +
                 fmaxf(s2, 0.f) * r2v.z + fmaxf(s3, 0.f) * r2v.w;
      float* redS = (float*)(smem + REDS);
      redS[(tid >> 6) * 64 + ii] = rp;
      __syncthreads();
      if (tid < 64) {
        float rv = rb2[0];
#pragma unroll
        for (int m = 0; m < 8; ++m) rv += redS[m * 64 + tid];
        int iG = i0 + tid;
        size_t tb = ((size_t)(b * NN + iG) * NKNOTS + ksp) * 2;
        float tgt = ca[tb];
        if (k == 11) tgt += cb[tb] + cc[tb] + cd[tb];   // frac=1: a+b+c+d
        float dv = rv - tgt;
        float ad = fabsf(dv);
        float hub = (ad < 1.f) ? 0.5f * dv * dv : (ad - 0.5f);
        hub += __shfl_down(hub, 32);
        hub += __shfl_down(hub, 16);
        hub += __shfl_down(hub, 8);
        hub += __shfl_down(hub, 4);
        hub += __shfl_down(hub, 2);
        hub += __shfl_down(hub, 1);
        if (tid == 0) atomicAdd(loss, hub);
      }
    }

    // ---- pred head (k == 11 only) ----
    if (k == 11) {
      __syncthreads();
      const int ii = tid & 63, mg4 = (tid >> 6) * 4;
      float s0 = pb1[mg4], s1 = pb1[mg4 + 1], s2 = pb1[mg4 + 2], s3 = pb1[mg4 + 3];
#pragma unroll 8
      for (int h = 0; h < 64; ++h) {
        unsigned int v = *(const unsigned int*)(smem + HT32 + h * 256 +
                           ((((ii >> 2) ^ (h & 15))) << 4) + (ii & 3) * 4);
        float f = bf2f((unsigned short)(v >> 16)) + bf2f((unsigned short)(v & 0xffff));
        float4 wv = *(const float4*)(pW1 + h * 32 + mg4);
        s0 = fmaf(f, wv.x, s0); s1 = fmaf(f, wv.y, s1);
        s2 = fmaf(f, wv.z, s2); s3 = fmaf(f, wv.w, s3);
      }
      float* pl1 = (float*)(smem + PL1);
      pl1[ii * 32 + mg4 + 0] = fmaxf(s0, 0.f);
      pl1[ii * 32 + mg4 + 1] = fmaxf(s1, 0.f);
      pl1[ii * 32 + mg4 + 2] = fmaxf(s2, 0.f);
      pl1[ii * 32 + mg4 + 3] = fmaxf(s3, 0.f);
      __syncthreads();
#pragma unroll
      for (int rep = 0; rep < 2; ++rep) {
        int idxp = tid + rep * 512;
        if (idxp < 768) {
          int i_ = idxp / 12, o = idxp % 12;
          float s = pb2[o];
#pragma unroll
          for (int m = 0; m < 32; ++m) s = fmaf(pl1[i_ * 32 + m], pW2[m * 12 + o], s);
          out[((size_t)b * NN + (i0 + i_)) * 12 + o] = s;
        }
      }
    }

    // ---- per-batch wait (16 arrivals, XCD-local) + L1-only invalidate ----
    __syncthreads();
    if (tid == 0) {
      unsigned int* ctr = &syncc[b * 32 + k];
      while (atomicAdd(ctr, 0u) < 16u) __builtin_amdgcn_s_sleep(1);
      asm volatile("buffer_inv sc0" ::: "memory");   // drop stale vector-L1
    }
    __syncthreads();
  }
}

__global__ void finalize_kernel(const float* __restrict__ loss, float* __restrict__ out)
{
  out[196608] = loss[0] * (1.0f / 196608.0f);
}

// -------------------------------------------------------------------------
extern "C" void kernel_launch(void* const* d_in, const int* in_sizes, int n_in,
                              void* d_out, int out_size, void* d_ws, size_t ws_size,
                              hipStream_t stream)
{
  const float* A     = (const float*)d_in[0];
  const float* delay = (const float*)d_in[1];
  const float* ca    = (const float*)d_in[2];
  const float* cb    = (const float*)d_in[3];
  const float* cc    = (const float*)d_in[4];
  const float* cd    = (const float*)d_in[5];
  const float* emb   = (const float*)d_in[6];
  const float* iW1   = (const float*)d_in[7];
  const float* ib1   = (const float*)d_in[8];
  const float* iW2   = (const float*)d_in[9];
  const float* ib2   = (const float*)d_in[10];
  const float* Wm    = (const float*)d_in[11];
  const float* Wsm   = (const float*)d_in[12];
  const float* Wx    = (const float*)d_in[13];
  const float* db    = (const float*)d_in[14];
  const float* rW1   = (const float*)d_in[15];
  const float* rb1   = (const float*)d_in[16];
  const float* rW2   = (const float*)d_in[17];
  const float* rb2   = (const float*)d_in[18];
  const float* pW1   = (const float*)d_in[19];
  const float* pb1   = (const float*)d_in[20];
  const float* pW2   = (const float*)d_in[21];
  const float* pb2   = (const float*)d_in[22];

  char* wsb = (char*)d_ws;
  float* out = (float*)d_out;
  unsigned short* Wpk  = (unsigned short*)(wsb + WPK_OFF);
  unsigned int*  M3g   = (unsigned int*)(wsb + M3_OFF);
  unsigned short* SThi = (unsigned short*)(wsb + STHI_OFF);
  unsigned short* STlo = (unsigned short*)(wsb + STLO_OFF);
  unsigned short* wgt  = (unsigned short*)(wsb + WGT_OFF);
  unsigned int* syncc  = (unsigned int*)(wsb + SYNC_OFF);
  float* loss          = (float*)(wsb + LOSS_OFF);
  float* Z             = (float*)(wsb + Z_OFF);
  float* dinv          = (float*)(wsb + DINV_OFF);

  hipMemsetAsync(syncc, 0, 2048 + 64, stream);   // sync counters + loss
  rowstats_kernel<<<NN, 256, 0, stream>>>(emb, A, Z, dinv);
  build_wt_kernel<<<256, 256, 0, stream>>>(emb, A, delay, Z, dinv, Wpk, M3g);
  init_s_kernel<<<288, 256, 0, stream>>>(ca, iW1, ib1, iW2, ib2,
                                         SThi, STlo, Wm, Wsm, wgt);
  scan_kernel<<<256, 512, 0, stream>>>(
      Wpk, M3g, SThi, STlo, wgt, syncc, Wx, db, cb, cc, cd, ca,
      rW1, rb1, rW2, rb2, pW1, pb1, pW2, pb2, out, loss);
  finalize_kernel<<<1, 1, 0, stream>>>(loss, out);
}

// Round 18
// 357.374 us; speedup vs baseline: 1.6957x; 1.0887x over previous
//
#include <hip/hip_runtime.h>
#include <cstddef>
#include <cstdint>

#define NN 1024
#define BB 16
#define NKNOTS 11

typedef __attribute__((ext_vector_type(8))) short short8_v;
typedef __attribute__((ext_vector_type(4))) float f32x4;
typedef __attribute__((ext_vector_type(8))) unsigned short ushort8_v;
typedef __attribute__((ext_vector_type(4))) unsigned short ushort4_v;
typedef __attribute__((ext_vector_type(4))) unsigned int uint4_v;
typedef __attribute__((ext_vector_type(2))) unsigned int uint2_v;

// ---- workspace byte offsets ----
#define WPK_OFF   ((size_t)0)                         // 1024x1024 bf16 = 2MB
#define M3_OFF    ((size_t)2 << 20)                   // 1024x128 u32 = 512KB
#define STHI_OFF  ((size_t)6 << 20)                   // 4 x 1M ushort = 8MB
#define STLO_OFF  ((size_t)14 << 20)                  // 8MB
#define WGT_OFF   ((size_t)22 << 20)                  // 16KB bf16 swizzled W^T
#define SYNC_OFF  (((size_t)22 << 20) + 16384)        // 16 batches x 32 u32
#define LOSS_OFF  (SYNC_OFF + 2048)
#define Z_OFF     (LOSS_OFF + 256)
#define DINV_OFF  (Z_OFF + 4096)

// ---- scan kernel LDS layout (bytes) ----
// GEMM: 4 bufs x 34816 @ 0/34816/69632/104448.
//   buf = [W 8K][M3 2K][B0 8K][B1 8K][B2 8K]; rows 128B = 8 chunks of 16B,
//   data chunk c stored at c^(row&7). M3: [64 rows][8 octs] u32 linear.
// Epilogue overlay (bufs dead after GEMM loop):
#define AGGS   0        // f32 [64][68]
#define AGGH   17408    // bf16 plane [64 i][64 c], row 128B, chunk^=(row&7)
#define AGGL   25600
#define HH_    33792    // bf16 plane [64 i][64 c] of h_k
#define HL_    41984
#define HT32   50176    // packed hi/lo u32 plane [64 c][64 i]
#define REDS   66560    // reg-head partials (2KB)
#define PL1    68608    // pred layer1 (8KB)
#define WGT_L  139264   // persistent: swizzled W^T bf16 (16KB)
#define LUT_OFF 155648  // persistent: 16 x 8B nibble->short4 mask LUT

__device__ __forceinline__ unsigned short f2bf(float x) {
  unsigned int u = __float_as_uint(x);
  return (unsigned short)((u + 0x7FFFu + ((u >> 16) & 1u)) >> 16);
}
__device__ __forceinline__ float bf2f(unsigned short h) {
  return __uint_as_float(((unsigned int)h) << 16);
}
__device__ __forceinline__ void gload16(const void* g, void* l) {
  __builtin_amdgcn_global_load_lds(
      (const __attribute__((address_space(1))) unsigned int*)g,
      (__attribute__((address_space(3))) unsigned int*)l, 16, 0, 0);
}
__device__ __forceinline__ void gload4(const void* g, void* l) {
  __builtin_amdgcn_global_load_lds(
      (const __attribute__((address_space(1))) unsigned int*)g,
      (__attribute__((address_space(3))) unsigned int*)l, 4, 0, 0);
}

// -------------------------------------------------------------------------
// Kernel 1: per-row softmax denominator Z[j] and degree rsqrt dinv[j]
// -------------------------------------------------------------------------
__global__ __launch_bounds__(256) void rowstats_kernel(
    const float* __restrict__ emb, const float* __restrict__ A,
    float* __restrict__ Z, float* __restrict__ dinv)
{
  const int j = blockIdx.x;
  const int tid = threadIdx.x;
  __shared__ float ej[64];
  __shared__ float r1[256], r2[256];
  if (tid < 64) ej[tid] = emb[j * 64 + tid];
  __syncthreads();
  float zs = 0.f, as = 0.f;
  for (int i = tid; i < NN; i += 256) {
    const float4* er = (const float4*)(emb + (size_t)i * 64);
    float dot = 0.f;
#pragma unroll
    for (int q = 0; q < 16; ++q) {
      float4 e = er[q];
      dot += e.x * ej[q * 4 + 0] + e.y * ej[q * 4 + 1] +
             e.z * ej[q * 4 + 2] + e.w * ej[q * 4 + 3];
    }
    zs += expf(fmaxf(dot, 0.f));
    as += A[(size_t)j * NN + i];
  }
  r1[tid] = zs; r2[tid] = as;
  __syncthreads();
  for (int s = 128; s > 0; s >>= 1) {
    if (tid < s) { r1[tid] += r1[tid + s]; r2[tid] += r2[tid + s]; }
    __syncthreads();
  }
  if (tid == 0) {
    Z[j] = r1[0];
    dinv[j] = rsqrtf(r2[0] + 1.0f);
  }
}

// -------------------------------------------------------------------------
// Kernel 2 (v3): build packed W (bf16, unmasked) + per-octet bin masks M3.
// -------------------------------------------------------------------------
__global__ __launch_bounds__(256) void build_wt_kernel(
    const float* __restrict__ emb, const float* __restrict__ A,
    const float* __restrict__ delay, const float* __restrict__ Z,
    const float* __restrict__ dinv,
    unsigned short* __restrict__ Wpk, unsigned int* __restrict__ M3g)
{
  __shared__ float eI[64][65];
  __shared__ float eJ[64][65];
  __shared__ float wS[64][65];     // [jj][ii]
  __shared__ unsigned char dS[64][64];
  __shared__ float diS[64];

  const int tid = threadIdx.x;
  const int it = blockIdx.x >> 4, jt = blockIdx.x & 15;
  const int i0 = it * 64, j0 = jt * 64;

  for (int q = tid; q < 4096; q += 256) {
    int r = q >> 6, c = q & 63;
    eI[r][c] = emb[(size_t)(i0 + r) * 64 + c];
    eJ[r][c] = emb[(size_t)(j0 + r) * 64 + c];
  }
  if (tid < 64) diS[tid] = dinv[i0 + tid];
  __syncthreads();

  const int jj = tid >> 2, iig = (tid & 3) * 16;
  float dotv[16];
#pragma unroll
  for (int m = 0; m < 16; ++m) dotv[m] = 0.f;
#pragma unroll 4
  for (int h4 = 0; h4 < 16; ++h4) {
    float4 a = *(const float4*)&eJ[jj][h4 * 4];
#pragma unroll
    for (int m = 0; m < 16; ++m) {
      float4 bb = *(const float4*)&eI[iig + m][h4 * 4];
      dotv[m] += a.x * bb.x + a.y * bb.y + a.z * bb.z + a.w * bb.w;
    }
  }
  const float Zj = Z[j0 + jj], dj = dinv[j0 + jj];
  const float* Ap = A + (size_t)(j0 + jj) * NN + i0 + iig;
  const float* Dp = delay + (size_t)(j0 + jj) * NN + i0 + iig;
#pragma unroll
  for (int m = 0; m < 16; ++m) {
    float aji = Ap[m] + ((i0 + iig + m) == (j0 + jj) ? 1.f : 0.f);
    float ac = expf(fmaxf(dotv[m], 0.f)) / Zj + dj * diS[iig + m] * aji;
    float w = (ac > 0.001f) ? ac : 0.f;
    float dl = fminf(fmaxf(Dp[m], 0.f), 2.f);
    wS[jj][iig + m] = w;
    dS[jj][iig + m] = (unsigned char)(int)rintf(dl);
  }
  __syncthreads();

  const int iw = tid >> 2, jg = (tid & 3) * 16;
  ushort8_v P0, P1;
#pragma unroll
  for (int m = 0; m < 8; ++m) {
    P0[m] = f2bf(wS[jg + m][iw]);
    P1[m] = f2bf(wS[jg + 8 + m][iw]);
  }
  size_t woff = (size_t)(i0 + iw) * NN + j0 + jg;
  *(ushort8_v*)(Wpk + woff) = P0;
  *(ushort8_v*)(Wpk + woff + 8) = P1;
  uint2_v mw;
#pragma unroll
  for (int o = 0; o < 2; ++o) {
    unsigned int m0 = 0, m1 = 0, m2 = 0;
#pragma unroll
    for (int e = 0; e < 8; ++e) {
      int dv = dS[jg + o * 8 + e][iw];
      m0 |= (dv == 0) << e;
      m1 |= (dv == 1) << e;
      m2 |= (dv == 2) << e;
    }
    mw[o] = m0 | (m1 << 8) | (m2 << 16);
  }
  *(uint2_v*)(M3g + (size_t)(i0 + iw) * 128 + (j0 + jg) / 8) = mw;
}

// -------------------------------------------------------------------------
// Kernel 3 (v2): init S slices 0,1; blocks 256..287 build swizzled W^T.
// -------------------------------------------------------------------------
__global__ __launch_bounds__(256) void init_s_kernel(
    const float* __restrict__ ca, const float* __restrict__ W1,
    const float* __restrict__ b1, const float* __restrict__ W2,
    const float* __restrict__ b2,
    unsigned short* __restrict__ SThi, unsigned short* __restrict__ STlo,
    const float* __restrict__ Wm, const float* __restrict__ Wsm,
    unsigned short* __restrict__ wgt)
{
  const int bid = blockIdx.x;
  const int tid = threadIdx.x;
  if (bid >= 256) {   // wgt part (chunk-swizzled per n)
    int e = (bid - 256) * 256 + tid;
    int n = e >> 7, kk = e & 127;
    float v = (kk < 64) ? Wm[kk * 64 + n] : Wsm[(kk - 64) * 64 + n];
    wgt[n * 128 + (((kk >> 3) ^ (n & 15)) << 3) + (kk & 7)] = f2bf(v);
    return;
  }
  __shared__ float l1S[64][65];
  __shared__ float W2S[64][128];
  __shared__ float hidS[64][129];

  const int nt = bid >> 4, b = bid & 15;
  const int n0 = nt * 64;

  for (int q = tid; q < 2048; q += 256)
    ((float4*)&W2S[0][0])[q] = ((const float4*)W2)[q];

  {
    const int n = tid >> 2, hb = (tid & 3) * 16;
    float2 x = *(const float2*)(ca + ((size_t)(b * NN + n0 + n) * NKNOTS) * 2);
#pragma unroll
    for (int m = 0; m < 16; ++m) {
      int h = hb + m;
      l1S[n][h] = fmaxf(x.x * W1[h] + x.y * W1[64 + h] + b1[h], 0.f);
    }
  }
  __syncthreads();
  {
    const int nn = tid & 63, o0 = (tid >> 6) * 32;
    float hid[32];
#pragma unroll
    for (int o = 0; o < 32; ++o) hid[o] = b2[o0 + o];
    for (int h = 0; h < 64; ++h) {
      float lv = l1S[nn][h];
#pragma unroll
      for (int o = 0; o < 32; ++o) hid[o] = fmaf(lv, W2S[h][o0 + o], hid[o]);
    }
#pragma unroll
    for (int o = 0; o < 32; ++o) hidS[nn][o0 + o] = hid[o];
  }
  __syncthreads();
  {
    const int r = tid >> 1, hf = tid & 1;
    const int t = r >> 6, hh = r & 63;
    size_t off = ((size_t)t << 20) + (size_t)(b * 64 + hh) * NN + n0 + hf * 32;
    ushort8_v H[4], L[4];
#pragma unroll
    for (int q = 0; q < 4; ++q)
#pragma unroll
      for (int m = 0; m < 8; ++m) {
        float v = hidS[hf * 32 + q * 8 + m][r];
        unsigned short hv = f2bf(v);
        H[q][m] = hv; L[q][m] = f2bf(v - bf2f(hv));
      }
#pragma unroll
    for (int q = 0; q < 4; ++q) {
      *(ushort8_v*)(SThi + off + q * 8) = H[q];
      *(ushort8_v*)(STlo + off + q * 8) = L[q];
    }
  }
}

// -------------------------------------------------------------------------
// Kernel 4: FUSED persistent scan, batch-local sync, PACKED-W GEMM,
//   GROUP-2 schedule: one s_barrier per TWO j-chunk iterations (9 barrier
//   events/step vs 17); pacing inside a group via per-wave counted vmcnt.
// -------------------------------------------------------------------------
__global__ __launch_bounds__(512, 2) void scan_kernel(
    const unsigned short* __restrict__ Wpk, const unsigned int* __restrict__ M3g,
    unsigned short* __restrict__ SThi, unsigned short* __restrict__ STlo,
    const unsigned short* __restrict__ wgt, unsigned int* __restrict__ syncc,
    const float* __restrict__ Wx, const float* __restrict__ db,
    const float* __restrict__ cb, const float* __restrict__ cc,
    const float* __restrict__ cd, const float* __restrict__ ca,
    const float* __restrict__ rW1, const float* __restrict__ rb1,
    const float* __restrict__ rW2, const float* __restrict__ rb2,
    const float* __restrict__ pW1, const float* __restrict__ pb1,
    const float* __restrict__ pW2, const float* __restrict__ pb2,
    float* __restrict__ out, float* __restrict__ loss)
{
  __shared__ __align__(16) char smem[155776];
  __shared__ float sWx[128];
  __shared__ float sdb[64];

  const int tid  = threadIdx.x;
  const int lane = tid & 63;
  const int w    = tid >> 6;            // wave 0..7
  const int bid  = blockIdx.x;
  // batch-local decode: bid%8 == b%8 -> batch pinned to one XCD
  const int i_t = bid >> 4;             // 0..15
  const int b   = bid & 15;             // batch
  const int i0 = i_t * 64, c0 = b * 64;

  const int wr = (w >> 1) & 1, wc = w & 1, kh = w >> 2;
  const int g = lane >> 4, l15 = lane & 15;

  if (tid < 128) sWx[tid] = Wx[tid];
  else if (tid < 192) sdb[tid - 128] = db[tid - 128];

  // nibble->short4 mask LUT (16 x 8B), persistent
  if (tid < 32) {
    int n = tid >> 1, half = tid & 1;
    unsigned int dw = half == 0
      ? (((n & 1) ? 0xFFFFu : 0u) | ((n & 2) ? 0xFFFF0000u : 0u))
      : (((n & 4) ? 0xFFFFu : 0u) | ((n & 8) ? 0xFFFF0000u : 0u));
    *(unsigned int*)(smem + LUT_OFF + n * 8 + half * 4) = dw;
  }

  // stage swizzled W^T bf16 (16KB) once, persistent @WGT_L
  gload16(wgt + (size_t)tid * 8,        smem + WGT_L + tid * 16);
  gload16(wgt + 4096 + (size_t)tid * 8, smem + WGT_L + 8192 + tid * 16);
  __syncthreads();   // drains wgt gloads; LUT visible

  // staging map: row = tid>>3 (0..63), ch = tid&7
  const int s_row = tid >> 3;
  const int s_ch  = tid & 7;
  const int s_cx  = (s_ch ^ (s_row & 7)) * 8;
  // fragment byte offsets
  const int koff  = kh * 4 + g;                       // chunk/oct index 0..7
  const int s16   = (koff ^ (l15 & 7)) << 4;
  const int rowA0 = wr * 32 + l15;
  const int rB0   = 10240 + (wc * 32 + l15) * 128 + s16;

  float (*aggS)[68] = (float (*)[68])(smem + AGGS);

  for (int k = 0; k < 12; ++k) {
    // ===== GEMM: 16 j-chunks, 3 bins/iter via mask-AND, group-2 sched ===
    f32x4 acc[2][2];
#pragma unroll
    for (int fr = 0; fr < 2; ++fr)
#pragma unroll
      for (int fc = 0; fc < 2; ++fc)
        acc[fr][fc] = (f32x4){0.f, 0.f, 0.f, 0.f};

    auto stage = [&](int t) {   // t = j-chunk 0..15; 5 loads/thread
      const int jc = t << 6;
      char* dst = smem + (t & 3) * 34816;
      gload16(Wpk + (size_t)(i0 + s_row) * NN + jc + s_cx, dst + tid * 16);
      gload4(M3g + (size_t)(i0 + s_row) * 128 + (jc >> 3) + s_ch,
             dst + 8192 + tid * 4);
#pragma unroll
      for (int d = 0; d < 3; ++d) {
        int td = k + 1 - d; if (td < 0) td = 0;
        gload16(SThi + ((size_t)(td & 3) << 20) +
                    (size_t)(c0 + s_row) * NN + jc + s_cx,
                dst + 10240 + d * 8192 + tid * 16);
      }
    };

    auto mfma_iter = [&](int t) {
      const char* bp = smem + (t & 3) * 34816;
      short8_v w0 = *(const short8_v*)(bp + rowA0 * 128 + s16);
      short8_v w1 = *(const short8_v*)(bp + (rowA0 + 16) * 128 + s16);
      unsigned int m0 = *(const unsigned int*)(bp + 8192 + rowA0 * 32 + koff * 4);
      unsigned int m1 = *(const unsigned int*)(bp + 8192 + (rowA0 + 16) * 32 + koff * 4);
      __builtin_amdgcn_s_setprio(1);
#pragma unroll
      for (int d = 0; d < 3; ++d) {
        unsigned int mb0 = (m0 >> (8 * d)) & 0xFF;
        unsigned int mb1 = (m1 >> (8 * d)) & 0xFF;
        uint2_v lo0 = *(const uint2_v*)(smem + LUT_OFF + (mb0 & 15) * 8);
        uint2_v hi0 = *(const uint2_v*)(smem + LUT_OFF + (mb0 >> 4) * 8);
        uint2_v lo1 = *(const uint2_v*)(smem + LUT_OFF + (mb1 & 15) * 8);
        uint2_v hi1 = *(const uint2_v*)(smem + LUT_OFF + (mb1 >> 4) * 8);
        short8_v a0 = w0, a1 = w1;
        unsigned int* a0p = (unsigned int*)&a0;
        unsigned int* a1p = (unsigned int*)&a1;
        a0p[0] &= lo0[0]; a0p[1] &= lo0[1]; a0p[2] &= hi0[0]; a0p[3] &= hi0[1];
        a1p[0] &= lo1[0]; a1p[1] &= lo1[1]; a1p[2] &= hi1[0]; a1p[3] &= hi1[1];
        short8_v b0 = *(const short8_v*)(bp + d * 8192 + rB0);
        short8_v b1 = *(const short8_v*)(bp + d * 8192 + rB0 + 16 * 128);
        acc[0][0] = __builtin_amdgcn_mfma_f32_16x16x32_bf16(a0, b0, acc[0][0], 0, 0, 0);
        acc[0][1] = __builtin_amdgcn_mfma_f32_16x16x32_bf16(a0, b1, acc[0][1], 0, 0, 0);
        acc[1][0] = __builtin_amdgcn_mfma_f32_16x16x32_bf16(a1, b0, acc[1][0], 0, 0, 0);
        acc[1][1] = __builtin_amdgcn_mfma_f32_16x16x32_bf16(a1, b1, acc[1][1], 0, 0, 0);
      }
      __builtin_amdgcn_s_setprio(0);
    };

    stage(0); stage(1);
    asm volatile("s_waitcnt vmcnt(5)" ::: "memory");   // stage(0) landed
    __builtin_amdgcn_s_barrier();

    for (int m = 0; m < 8; ++m) {
      if (m < 7) { stage(2 * m + 2); stage(2 * m + 3); }
      // iter A = 2m: wait for its buffer (counted, per-wave, no barrier)
      if (m < 7) asm volatile("s_waitcnt vmcnt(15)" ::: "memory");
      else       asm volatile("s_waitcnt vmcnt(5)" ::: "memory");
      mfma_iter(2 * m);
      // iter B = 2m+1
      if (m < 7) asm volatile("s_waitcnt vmcnt(10)" ::: "memory");
      else       asm volatile("s_waitcnt vmcnt(0)" ::: "memory");
      mfma_iter(2 * m + 1);
      __builtin_amdgcn_sched_barrier(0);
      __builtin_amdgcn_s_barrier();      // one barrier per 2 iterations
    }
    __syncthreads();   // last buf reads done; LDS reusable

    // ---- merge kh halves into aggS (fp32) ----
    if (kh == 0) {
#pragma unroll
      for (int fr = 0; fr < 2; ++fr)
#pragma unroll
        for (int fc = 0; fc < 2; ++fc)
#pragma unroll
          for (int rr = 0; rr < 4; ++rr)
            aggS[wr * 32 + fr * 16 + g * 4 + rr][wc * 32 + fc * 16 + l15] = acc[fr][fc][rr];
    }
    __syncthreads();
    if (kh == 1) {
#pragma unroll
      for (int fr = 0; fr < 2; ++fr)
#pragma unroll
        for (int fc = 0; fc < 2; ++fc)
#pragma unroll
          for (int rr = 0; rr < 4; ++rr)
            aggS[wr * 32 + fr * 16 + g * 4 + rr][wc * 32 + fc * 16 + l15] += acc[fr][fc][rr];
    }
    __syncthreads();

    // ---- aggS -> bf16 hi/lo planes (chunk-swizzled) ----
    {
      const int row = tid >> 3, c8 = tid & 7;
      const float* src = &aggS[row][c8 * 8];
      ushort8_v H, L;
#pragma unroll
      for (int q = 0; q < 8; ++q) {
        float f = src[q];
        unsigned short hv = f2bf(f);
        H[q] = hv; L[q] = f2bf(f - bf2f(hv));
      }
      const int pos = (c8 ^ (row & 7)) << 4;
      *(ushort8_v*)(smem + AGGH + row * 128 + pos) = H;
      *(ushort8_v*)(smem + AGGL + row * 128 + pos) = L;
    }
    // ---- stage h_k -> hH/hL planes ----
    {
      const int cl = tid >> 3, ich = (tid & 7) * 8;
      size_t off = ((size_t)((k + 1) & 3) << 20) + (size_t)(c0 + cl) * NN + (i0 + ich);
      ushort8_v h8 = *(const ushort8_v*)(SThi + off);
      ushort8_v l8 = *(const ushort8_v*)(STlo + off);
#pragma unroll
      for (int q = 0; q < 8; ++q) {
        int i = ich + q;
        int byo = i * 128 + ((((cl >> 3) ^ (i & 7))) << 4) + (cl & 7) * 2;
        *(unsigned short*)(smem + HH_ + byo) = h8[q];
        *(unsigned short*)(smem + HL_ + byo) = l8[q];
      }
    }
    __syncthreads();

    // ---- MFMA mini-GEMM: pre = [agg|h](64x128) @ W^T-frags (K=128) ----
    const int mr = w & 3, nc = w >> 2;   // 4 row-frags x 2 col-pairs
    f32x4 pacc[2];
    pacc[0] = (f32x4){0.f, 0.f, 0.f, 0.f};
    pacc[1] = (f32x4){0.f, 0.f, 0.f, 0.f};
#pragma unroll
    for (int ks = 0; ks < 4; ++ks) {
      const int base = (ks < 2) ? AGGH : HH_;
      const int ks2 = ks & 1;
      const int cxa = ((ks2 * 4 + g) ^ (l15 & 7)) << 4;
      const char* ra = smem + base + (mr * 16 + l15) * 128 + cxa;
      short8_v aH = *(const short8_v*)ra;
      short8_v aL = *(const short8_v*)(ra + 8192);
#pragma unroll
      for (int fc = 0; fc < 2; ++fc) {
        const int n = (nc * 2 + fc) * 16 + l15;
        const int cxb = ((ks * 4 + g) ^ l15) << 4;
        short8_v bv = *(const short8_v*)(smem + WGT_L + n * 256 + cxb);
        pacc[fc] = __builtin_amdgcn_mfma_f32_16x16x32_bf16(aH, bv, pacc[fc], 0, 0, 0);
        pacc[fc] = __builtin_amdgcn_mfma_f32_16x16x32_bf16(aL, bv, pacc[fc], 0, 0, 0);
      }
    }
    __syncthreads();   // plane reads done before HT32 overlay writes

    // ---- dx@Wx + bias, tanh; write ST ring + packed hT32 plane ----
    const int ksp = (k < 11) ? k : 10;
    float hn[2][4];
#pragma unroll
    for (int rr = 0; rr < 4; ++rr) {
      int iG = i0 + mr * 16 + g * 4 + rr;
      size_t cbase = ((size_t)(b * NN + iG) * NKNOTS + ksp) * 2;
      float dx0 = cb[cbase + 0], dx1 = cb[cbase + 1];
      if (k == 11) {   // frac = 1: der = b + 2c + 3d
        dx0 += 2.f * cc[cbase + 0] + 3.f * cd[cbase + 0];
        dx1 += 2.f * cc[cbase + 1] + 3.f * cd[cbase + 1];
      }
#pragma unroll
      for (int fc = 0; fc < 2; ++fc) {
        int hcol = (nc * 2 + fc) * 16 + l15;
        float pre = pacc[fc][rr] + dx0 * sWx[hcol] + dx1 * sWx[64 + hcol] + sdb[hcol];
        hn[fc][rr] = tanhf(pre);
      }
    }
#pragma unroll
    for (int fc = 0; fc < 2; ++fc) {
      int hcol = (nc * 2 + fc) * 16 + l15;
      int iG0 = i0 + mr * 16 + g * 4;
      size_t off2 = ((size_t)((k + 2) & 3) << 20) + (size_t)(c0 + hcol) * NN + iG0;
      ushort4_v H4, L4;
      uint4_v pk;
#pragma unroll
      for (int rr = 0; rr < 4; ++rr) {
        unsigned short hv = f2bf(hn[fc][rr]);
        unsigned short lv = f2bf(hn[fc][rr] - bf2f(hv));
        H4[rr] = hv; L4[rr] = lv;
        pk[rr] = ((unsigned int)hv << 16) | lv;
      }
      *(ushort4_v*)(SThi + off2) = H4;
      *(ushort4_v*)(STlo + off2) = L4;
      const int ci = mr * 4 + g;           // i-chunk (4 i's = 16B)
      *(uint4_v*)(smem + HT32 + hcol * 256 + ((ci ^ (hcol & 15)) << 4)) = pk;
    }
    // ---- signal-early: ST stores are L2-visible after vmcnt(0) drain ----
    asm volatile("s_waitcnt vmcnt(0)" ::: "memory");
    __syncthreads();                        // all threads' stores drained
    if (tid == 0) atomicAdd(&syncc[b * 32 + k], 1u);

    // ---- reg head + Huber (h_new from hT32 plane) ----
    {
      const int ii = tid & 63, mg4 = (tid >> 6) * 4;
      float s0 = rb1[mg4], s1 = rb1[mg4 + 1], s2 = rb1[mg4 + 2], s3 = rb1[mg4 + 3];
#pragma unroll 8
      for (int h = 0; h < 64; ++h) {
        unsigned int v = *(const unsigned int*)(smem + HT32 + h * 256 +
                           ((((ii >> 2) ^ (h & 15))) << 4) + (ii & 3) * 4);
        float f = bf2f((unsigned short)(v >> 16)) + bf2f((unsigned short)(v & 0xffff));
        float4 wv = *(const float4*)(rW1 + h * 32 + mg4);
        s0 = fmaf(f, wv.x, s0); s1 = fmaf(f, wv.y, s1);
        s2 = fmaf(f, wv.z, s2); s3 = fmaf(f, wv.w, s3);
      }
      float4 r2v = *(const float4*)(rW2 + mg4);
      float rp = fmaxf(s0, 0.f) * r2v.x + fmaxf(s1, 0.f) * r2v.y +
                 fmaxf(s2, 0.f) * r2v.z + fmaxf(s3, 0.f) * r2v.w;
      float* redS = (float*)(smem + REDS);
      redS[(tid >> 6) * 64 + ii] = rp;
      __syncthreads();
      if (tid < 64) {
        float rv = rb2[0];
#pragma unroll
        for (int m = 0; m < 8; ++m) rv += redS[m * 64 + tid];
        int iG = i0 + tid;
        size_t tb = ((size_t)(b * NN + iG) * NKNOTS + ksp) * 2;
        float tgt = ca[tb];
        if (k == 11) tgt += cb[tb] + cc[tb] + cd[tb];   // frac=1: a+b+c+d
        float dv = rv - tgt;
        float ad = fabsf(dv);
        float hub = (ad < 1.f) ? 0.5f * dv * dv : (ad - 0.5f);
        hub += __shfl_down(hub, 32);
        hub += __shfl_down(hub, 16);
        hub += __shfl_down(hub, 8);
        hub += __shfl_down(hub, 4);
        hub += __shfl_down(hub, 2);
        hub += __shfl_down(hub, 1);
        if (tid == 0) atomicAdd(loss, hub);
      }
    }

    // ---- pred head (k == 11 only) ----
    if (k == 11) {
      __syncthreads();
      const int ii = tid & 63, mg4 = (tid >> 6) * 4;
      float s0 = pb1[mg4], s1 = pb1[mg4 + 1], s2 = pb1[mg4 + 2], s3 = pb1[mg4 + 3];
#pragma unroll 8
      for (int h = 0; h < 64; ++h) {
        unsigned int v = *(const unsigned int*)(smem + HT32 + h * 256 +
                           ((((ii >> 2) ^ (h & 15))) << 4) + (ii & 3) * 4);
        float f = bf2f((unsigned short)(v >> 16)) + bf2f((unsigned short)(v & 0xffff));
        float4 wv = *(const float4*)(pW1 + h * 32 + mg4);
        s0 = fmaf(f, wv.x, s0); s1 = fmaf(f, wv.y, s1);
        s2 = fmaf(f, wv.z, s2); s3 = fmaf(f, wv.w, s3);
      }
      float* pl1 = (float*)(smem + PL1);
      pl1[ii * 32 + mg4 + 0] = fmaxf(s0, 0.f);
      pl1[ii * 32 + mg4 + 1] = fmaxf(s1, 0.f);
      pl1[ii * 32 + mg4 + 2] = fmaxf(s2, 0.f);
      pl1[ii * 32 + mg4 + 3] = fmaxf(s3, 0.f);
      __syncthreads();
#pragma unroll
      for (int rep = 0; rep < 2; ++rep) {
        int idxp = tid + rep * 512;
        if (idxp < 768) {
          int i_ = idxp / 12, o = idxp % 12;
          float s = pb2[o];
#pragma unroll
          for (int m = 0; m < 32; ++m) s = fmaf(pl1[i_ * 32 + m], pW2[m * 12 + o], s);
          out[((size_t)b * NN + (i0 + i_)) * 12 + o] = s;
        }
      }
    }

    // ---- per-batch wait (16 arrivals, XCD-local) + L1-only invalidate ----
    __syncthreads();
    if (tid == 0) {
      unsigned int* ctr = &syncc[b * 32 + k];
      while (atomicAdd(ctr, 0u) < 16u) __builtin_amdgcn_s_sleep(1);
      asm volatile("buffer_inv sc0" ::: "memory");   // drop stale vector-L1
    }
    __syncthreads();
  }
}

__global__ void finalize_kernel(const float* __restrict__ loss, float* __restrict__ out)
{
  out[196608] = loss[0] * (1.0f / 196608.0f);
}

// -------------------------------------------------------------------------
extern "C" void kernel_launch(void* const* d_in, const int* in_sizes, int n_in,
                              void* d_out, int out_size, void* d_ws, size_t ws_size,
                              hipStream_t stream)
{
  const float* A     = (const float*)d_in[0];
  const float* delay = (const float*)d_in[1];
  const float* ca    = (const float*)d_in[2];
  const float* cb    = (const float*)d_in[3];
  const float* cc    = (const float*)d_in[4];
  const float* cd    = (const float*)d_in[5];
  const float* emb   = (const float*)d_in[6];
  const float* iW1   = (const float*)d_in[7];
  const float* ib1   = (const float*)d_in[8];
  const float* iW2   = (const float*)d_in[9];
  const float* ib2   = (const float*)d_in[10];
  const float* Wm    = (const float*)d_in[11];
  const float* Wsm   = (const float*)d_in[12];
  const float* Wx    = (const float*)d_in[13];
  const float* db    = (const float*)d_in[14];
  const float* rW1   = (const float*)d_in[15];
  const float* rb1   = (const float*)d_in[16];
  const float* rW2   = (const float*)d_in[17];
  const float* rb2   = (const float*)d_in[18];
  const float* pW1   = (const float*)d_in[19];
  const float* pb1   = (const float*)d_in[20];
  const float* pW2   = (const float*)d_in[21];
  const float* pb2   = (const float*)d_in[22];

  char* wsb = (char*)d_ws;
  float* out = (float*)d_out;
  unsigned short* Wpk  = (unsigned short*)(wsb + WPK_OFF);
  unsigned int*  M3g   = (unsigned int*)(wsb + M3_OFF);
  unsigned short* SThi = (unsigned short*)(wsb + STHI_OFF);
  unsigned short* STlo = (unsigned short*)(wsb + STLO_OFF);
  unsigned short* wgt  = (unsigned short*)(wsb + WGT_OFF);
  unsigned int* syncc  = (unsigned int*)(wsb + SYNC_OFF);
  float* loss          = (float*)(wsb + LOSS_OFF);
  float* Z             = (float*)(wsb + Z_OFF);
  float* dinv          = (float*)(wsb + DINV_OFF);

  hipMemsetAsync(syncc, 0, 2048 + 64, stream);   // sync counters + loss
  rowstats_kernel<<<NN, 256, 0, stream>>>(emb, A, Z, dinv);
  build_wt_kernel<<<256, 256, 0, stream>>>(emb, A, delay, Z, dinv, Wpk, M3g);
  init_s_kernel<<<288, 256, 0, stream>>>(ca, iW1, ib1, iW2, ib2,
                                         SThi, STlo, Wm, Wsm, wgt);
  scan_kernel<<<256, 512, 0, stream>>>(
      Wpk, M3g, SThi, STlo, wgt, syncc, Wx, db, cb, cc, cd, ca,
      rW1, rb1, rW2, rb2, pW1, pb1, pW2, pb2, out, loss);
  finalize_kernel<<<1, 1, 0, stream>>>(loss, out);
}

// Round 19
// 356.694 us; speedup vs baseline: 1.6989x; 1.0019x over previous
//
#include <hip/hip_runtime.h>
#include <cstddef>
#include <cstdint>

#define NN 1024
#define BB 16
#define NKNOTS 11

typedef __attribute__((ext_vector_type(8))) short short8_v;
typedef __attribute__((ext_vector_type(4))) float f32x4;
typedef __attribute__((ext_vector_type(8))) unsigned short ushort8_v;
typedef __attribute__((ext_vector_type(4))) unsigned short ushort4_v;
typedef __attribute__((ext_vector_type(4))) unsigned int uint4_v;
typedef __attribute__((ext_vector_type(2))) unsigned int uint2_v;

// ---- workspace byte offsets ----
#define WPK_OFF   ((size_t)0)                         // 1024x1024 bf16 = 2MB
#define M3_OFF    ((size_t)2 << 20)                   // 1024x128 u32 = 512KB
#define STHI_OFF  ((size_t)6 << 20)                   // 4 x 1M ushort = 8MB
#define STLO_OFF  ((size_t)14 << 20)                  // 8MB
#define WGT_OFF   ((size_t)22 << 20)                  // 16KB bf16 swizzled W^T
#define SYNC_OFF  (((size_t)22 << 20) + 16384)        // 16 batches x 32 u32
#define LOSS_OFF  (SYNC_OFF + 2048)
#define Z_OFF     (LOSS_OFF + 256)
#define DINV_OFF  (Z_OFF + 4096)

// ---- scan kernel LDS layout (bytes) ----
// GEMM: 4 bufs x 34816 @ 0/34816/69632/104448.
//   buf = [W 8K][M3 2K][B0 8K][B1 8K][B2 8K]; rows 128B = 8 chunks of 16B,
//   data chunk c stored at c^(row&7). M3: [64 rows][8 octs] u32 linear.
// Epilogue overlay (bufs dead after GEMM loop):
#define AGGS   0        // f32 [64][68]  (kh=0 half)
#define AGGH   17408    // bf16 plane [64 i][64 c], row 128B, chunk^=(row&7)
#define AGGL   25600
#define HH_    33792    // bf16 plane [64 i][64 c] of h_k
#define HL_    41984
#define HT32   50176    // packed hi/lo u32 plane [64 c][64 i]
#define REDS   66560    // reg-head partials (2KB)
#define PL1    68608    // pred layer1 (8KB)
#define AGGS2  76800    // f32 [64][68]  (kh=1 half; inside dead buf2)
#define WGT_L  139264   // persistent: swizzled W^T bf16 (16KB)
#define LUT_OFF 155648  // persistent: 16 x 8B nibble->short4 mask LUT

__device__ __forceinline__ unsigned short f2bf(float x) {
  unsigned int u = __float_as_uint(x);
  return (unsigned short)((u + 0x7FFFu + ((u >> 16) & 1u)) >> 16);
}
__device__ __forceinline__ float bf2f(unsigned short h) {
  return __uint_as_float(((unsigned int)h) << 16);
}
__device__ __forceinline__ void gload16(const void* g, void* l) {
  __builtin_amdgcn_global_load_lds(
      (const __attribute__((address_space(1))) unsigned int*)g,
      (__attribute__((address_space(3))) unsigned int*)l, 16, 0, 0);
}
__device__ __forceinline__ void gload4(const void* g, void* l) {
  __builtin_amdgcn_global_load_lds(
      (const __attribute__((address_space(1))) unsigned int*)g,
      (__attribute__((address_space(3))) unsigned int*)l, 4, 0, 0);
}

// -------------------------------------------------------------------------
// Kernel 1: per-row softmax denominator Z[j] and degree rsqrt dinv[j]
// -------------------------------------------------------------------------
__global__ __launch_bounds__(256) void rowstats_kernel(
    const float* __restrict__ emb, const float* __restrict__ A,
    float* __restrict__ Z, float* __restrict__ dinv)
{
  const int j = blockIdx.x;
  const int tid = threadIdx.x;
  __shared__ float ej[64];
  __shared__ float r1[256], r2[256];
  if (tid < 64) ej[tid] = emb[j * 64 + tid];
  __syncthreads();
  float zs = 0.f, as = 0.f;
  for (int i = tid; i < NN; i += 256) {
    const float4* er = (const float4*)(emb + (size_t)i * 64);
    float dot = 0.f;
#pragma unroll
    for (int q = 0; q < 16; ++q) {
      float4 e = er[q];
      dot += e.x * ej[q * 4 + 0] + e.y * ej[q * 4 + 1] +
             e.z * ej[q * 4 + 2] + e.w * ej[q * 4 + 3];
    }
    zs += expf(fmaxf(dot, 0.f));
    as += A[(size_t)j * NN + i];
  }
  r1[tid] = zs; r2[tid] = as;
  __syncthreads();
  for (int s = 128; s > 0; s >>= 1) {
    if (tid < s) { r1[tid] += r1[tid + s]; r2[tid] += r2[tid + s]; }
    __syncthreads();
  }
  if (tid == 0) {
    Z[j] = r1[0];
    dinv[j] = rsqrtf(r2[0] + 1.0f);
  }
}

// -------------------------------------------------------------------------
// Kernel 2 (v3): build packed W (bf16, unmasked) + per-octet bin masks M3.
// -------------------------------------------------------------------------
__global__ __launch_bounds__(256) void build_wt_kernel(
    const float* __restrict__ emb, const float* __restrict__ A,
    const float* __restrict__ delay, const float* __restrict__ Z,
    const float* __restrict__ dinv,
    unsigned short* __restrict__ Wpk, unsigned int* __restrict__ M3g)
{
  __shared__ float eI[64][65];
  __shared__ float eJ[64][65];
  __shared__ float wS[64][65];     // [jj][ii]
  __shared__ unsigned char dS[64][64];
  __shared__ float diS[64];

  const int tid = threadIdx.x;
  const int it = blockIdx.x >> 4, jt = blockIdx.x & 15;
  const int i0 = it * 64, j0 = jt * 64;

  for (int q = tid; q < 4096; q += 256) {
    int r = q >> 6, c = q & 63;
    eI[r][c] = emb[(size_t)(i0 + r) * 64 + c];
    eJ[r][c] = emb[(size_t)(j0 + r) * 64 + c];
  }
  if (tid < 64) diS[tid] = dinv[i0 + tid];
  __syncthreads();

  const int jj = tid >> 2, iig = (tid & 3) * 16;
  float dotv[16];
#pragma unroll
  for (int m = 0; m < 16; ++m) dotv[m] = 0.f;
#pragma unroll 4
  for (int h4 = 0; h4 < 16; ++h4) {
    float4 a = *(const float4*)&eJ[jj][h4 * 4];
#pragma unroll
    for (int m = 0; m < 16; ++m) {
      float4 bb = *(const float4*)&eI[iig + m][h4 * 4];
      dotv[m] += a.x * bb.x + a.y * bb.y + a.z * bb.z + a.w * bb.w;
    }
  }
  const float Zj = Z[j0 + jj], dj = dinv[j0 + jj];
  const float* Ap = A + (size_t)(j0 + jj) * NN + i0 + iig;
  const float* Dp = delay + (size_t)(j0 + jj) * NN + i0 + iig;
#pragma unroll
  for (int m = 0; m < 16; ++m) {
    float aji = Ap[m] + ((i0 + iig + m) == (j0 + jj) ? 1.f : 0.f);
    float ac = expf(fmaxf(dotv[m], 0.f)) / Zj + dj * diS[iig + m] * aji;
    float w = (ac > 0.001f) ? ac : 0.f;
    float dl = fminf(fmaxf(Dp[m], 0.f), 2.f);
    wS[jj][iig + m] = w;
    dS[jj][iig + m] = (unsigned char)(int)rintf(dl);
  }
  __syncthreads();

  const int iw = tid >> 2, jg = (tid & 3) * 16;
  ushort8_v P0, P1;
#pragma unroll
  for (int m = 0; m < 8; ++m) {
    P0[m] = f2bf(wS[jg + m][iw]);
    P1[m] = f2bf(wS[jg + 8 + m][iw]);
  }
  size_t woff = (size_t)(i0 + iw) * NN + j0 + jg;
  *(ushort8_v*)(Wpk + woff) = P0;
  *(ushort8_v*)(Wpk + woff + 8) = P1;
  uint2_v mw;
#pragma unroll
  for (int o = 0; o < 2; ++o) {
    unsigned int m0 = 0, m1 = 0, m2 = 0;
#pragma unroll
    for (int e = 0; e < 8; ++e) {
      int dv = dS[jg + o * 8 + e][iw];
      m0 |= (dv == 0) << e;
      m1 |= (dv == 1) << e;
      m2 |= (dv == 2) << e;
    }
    mw[o] = m0 | (m1 << 8) | (m2 << 16);
  }
  *(uint2_v*)(M3g + (size_t)(i0 + iw) * 128 + (j0 + jg) / 8) = mw;
}

// -------------------------------------------------------------------------
// Kernel 3 (v2): init S slices 0,1; blocks 256..287 build swizzled W^T.
// -------------------------------------------------------------------------
__global__ __launch_bounds__(256) void init_s_kernel(
    const float* __restrict__ ca, const float* __restrict__ W1,
    const float* __restrict__ b1, const float* __restrict__ W2,
    const float* __restrict__ b2,
    unsigned short* __restrict__ SThi, unsigned short* __restrict__ STlo,
    const float* __restrict__ Wm, const float* __restrict__ Wsm,
    unsigned short* __restrict__ wgt)
{
  const int bid = blockIdx.x;
  const int tid = threadIdx.x;
  if (bid >= 256) {   // wgt part (chunk-swizzled per n)
    int e = (bid - 256) * 256 + tid;
    int n = e >> 7, kk = e & 127;
    float v = (kk < 64) ? Wm[kk * 64 + n] : Wsm[(kk - 64) * 64 + n];
    wgt[n * 128 + (((kk >> 3) ^ (n & 15)) << 3) + (kk & 7)] = f2bf(v);
    return;
  }
  __shared__ float l1S[64][65];
  __shared__ float W2S[64][128];
  __shared__ float hidS[64][129];

  const int nt = bid >> 4, b = bid & 15;
  const int n0 = nt * 64;

  for (int q = tid; q < 2048; q += 256)
    ((float4*)&W2S[0][0])[q] = ((const float4*)W2)[q];

  {
    const int n = tid >> 2, hb = (tid & 3) * 16;
    float2 x = *(const float2*)(ca + ((size_t)(b * NN + n0 + n) * NKNOTS) * 2);
#pragma unroll
    for (int m = 0; m < 16; ++m) {
      int h = hb + m;
      l1S[n][h] = fmaxf(x.x * W1[h] + x.y * W1[64 + h] + b1[h], 0.f);
    }
  }
  __syncthreads();
  {
    const int nn = tid & 63, o0 = (tid >> 6) * 32;
    float hid[32];
#pragma unroll
    for (int o = 0; o < 32; ++o) hid[o] = b2[o0 + o];
    for (int h = 0; h < 64; ++h) {
      float lv = l1S[nn][h];
#pragma unroll
      for (int o = 0; o < 32; ++o) hid[o] = fmaf(lv, W2S[h][o0 + o], hid[o]);
    }
#pragma unroll
    for (int o = 0; o < 32; ++o) hidS[nn][o0 + o] = hid[o];
  }
  __syncthreads();
  {
    const int r = tid >> 1, hf = tid & 1;
    const int t = r >> 6, hh = r & 63;
    size_t off = ((size_t)t << 20) + (size_t)(b * 64 + hh) * NN + n0 + hf * 32;
    ushort8_v H[4], L[4];
#pragma unroll
    for (int q = 0; q < 4; ++q)
#pragma unroll
      for (int m = 0; m < 8; ++m) {
        float v = hidS[hf * 32 + q * 8 + m][r];
        unsigned short hv = f2bf(v);
        H[q][m] = hv; L[q][m] = f2bf(v - bf2f(hv));
      }
#pragma unroll
    for (int q = 0; q < 4; ++q) {
      *(ushort8_v*)(SThi + off + q * 8) = H[q];
      *(ushort8_v*)(STlo + off + q * 8) = L[q];
    }
  }
}

// -------------------------------------------------------------------------
// Kernel 4: FUSED persistent scan, batch-local sync, PACKED-W GEMM,
//   GROUP-2 barrier schedule + minimized epilogue barriers (15 events/step).
// -------------------------------------------------------------------------
__global__ __launch_bounds__(512, 2) void scan_kernel(
    const unsigned short* __restrict__ Wpk, const unsigned int* __restrict__ M3g,
    unsigned short* __restrict__ SThi, unsigned short* __restrict__ STlo,
    const unsigned short* __restrict__ wgt, unsigned int* __restrict__ syncc,
    const float* __restrict__ Wx, const float* __restrict__ db,
    const float* __restrict__ cb, const float* __restrict__ cc,
    const float* __restrict__ cd, const float* __restrict__ ca,
    const float* __restrict__ rW1, const float* __restrict__ rb1,
    const float* __restrict__ rW2, const float* __restrict__ rb2,
    const float* __restrict__ pW1, const float* __restrict__ pb1,
    const float* __restrict__ pW2, const float* __restrict__ pb2,
    float* __restrict__ out, float* __restrict__ loss)
{
  __shared__ __align__(16) char smem[155776];
  __shared__ float sWx[128];
  __shared__ float sdb[64];

  const int tid  = threadIdx.x;
  const int lane = tid & 63;
  const int w    = tid >> 6;            // wave 0..7
  const int bid  = blockIdx.x;
  // batch-local decode: bid%8 == b%8 -> batch pinned to one XCD
  const int i_t = bid >> 4;             // 0..15
  const int b   = bid & 15;             // batch
  const int i0 = i_t * 64, c0 = b * 64;

  const int wr = (w >> 1) & 1, wc = w & 1, kh = w >> 2;
  const int g = lane >> 4, l15 = lane & 15;

  if (tid < 128) sWx[tid] = Wx[tid];
  else if (tid < 192) sdb[tid - 128] = db[tid - 128];

  // nibble->short4 mask LUT (16 x 8B), persistent
  if (tid < 32) {
    int n = tid >> 1, half = tid & 1;
    unsigned int dw = half == 0
      ? (((n & 1) ? 0xFFFFu : 0u) | ((n & 2) ? 0xFFFF0000u : 0u))
      : (((n & 4) ? 0xFFFFu : 0u) | ((n & 8) ? 0xFFFF0000u : 0u));
    *(unsigned int*)(smem + LUT_OFF + n * 8 + half * 4) = dw;
  }

  // stage swizzled W^T bf16 (16KB) once, persistent @WGT_L
  gload16(wgt + (size_t)tid * 8,        smem + WGT_L + tid * 16);
  gload16(wgt + 4096 + (size_t)tid * 8, smem + WGT_L + 8192 + tid * 16);
  __syncthreads();   // drains wgt gloads; LUT visible

  // staging map: row = tid>>3 (0..63), ch = tid&7
  const int s_row = tid >> 3;
  const int s_ch  = tid & 7;
  const int s_cx  = (s_ch ^ (s_row & 7)) * 8;
  // fragment byte offsets
  const int koff  = kh * 4 + g;                       // chunk/oct index 0..7
  const int s16   = (koff ^ (l15 & 7)) << 4;
  const int rowA0 = wr * 32 + l15;
  const int rB0   = 10240 + (wc * 32 + l15) * 128 + s16;

  float (*aggS)[68]  = (float (*)[68])(smem + AGGS);
  float (*aggS2)[68] = (float (*)[68])(smem + AGGS2);

  for (int k = 0; k < 12; ++k) {
    // ===== GEMM: 16 j-chunks, 3 bins/iter via mask-AND, group-2 sched ===
    f32x4 acc[2][2];
#pragma unroll
    for (int fr = 0; fr < 2; ++fr)
#pragma unroll
      for (int fc = 0; fc < 2; ++fc)
        acc[fr][fc] = (f32x4){0.f, 0.f, 0.f, 0.f};

    auto stage = [&](int t) {   // t = j-chunk 0..15; 5 loads/thread
      const int jc = t << 6;
      char* dst = smem + (t & 3) * 34816;
      gload16(Wpk + (size_t)(i0 + s_row) * NN + jc + s_cx, dst + tid * 16);
      gload4(M3g + (size_t)(i0 + s_row) * 128 + (jc >> 3) + s_ch,
             dst + 8192 + tid * 4);
#pragma unroll
      for (int d = 0; d < 3; ++d) {
        int td = k + 1 - d; if (td < 0) td = 0;
        gload16(SThi + ((size_t)(td & 3) << 20) +
                    (size_t)(c0 + s_row) * NN + jc + s_cx,
                dst + 10240 + d * 8192 + tid * 16);
      }
    };

    auto mfma_iter = [&](int t) {
      const char* bp = smem + (t & 3) * 34816;
      short8_v w0 = *(const short8_v*)(bp + rowA0 * 128 + s16);
      short8_v w1 = *(const short8_v*)(bp + (rowA0 + 16) * 128 + s16);
      unsigned int m0 = *(const unsigned int*)(bp + 8192 + rowA0 * 32 + koff * 4);
      unsigned int m1 = *(const unsigned int*)(bp + 8192 + (rowA0 + 16) * 32 + koff * 4);
      __builtin_amdgcn_s_setprio(1);
#pragma unroll
      for (int d = 0; d < 3; ++d) {
        unsigned int mb0 = (m0 >> (8 * d)) & 0xFF;
        unsigned int mb1 = (m1 >> (8 * d)) & 0xFF;
        uint2_v lo0 = *(const uint2_v*)(smem + LUT_OFF + (mb0 & 15) * 8);
        uint2_v hi0 = *(const uint2_v*)(smem + LUT_OFF + (mb0 >> 4) * 8);
        uint2_v lo1 = *(const uint2_v*)(smem + LUT_OFF + (mb1 & 15) * 8);
        uint2_v hi1 = *(const uint2_v*)(smem + LUT_OFF + (mb1 >> 4) * 8);
        short8_v a0 = w0, a1 = w1;
        unsigned int* a0p = (unsigned int*)&a0;
        unsigned int* a1p = (unsigned int*)&a1;
        a0p[0] &= lo0[0]; a0p[1] &= lo0[1]; a0p[2] &= hi0[0]; a0p[3] &= hi0[1];
        a1p[0] &= lo1[0]; a1p[1] &= lo1[1]; a1p[2] &= hi1[0]; a1p[3] &= hi1[1];
        short8_v b0 = *(const short8_v*)(bp + d * 8192 + rB0);
        short8_v b1 = *(const short8_v*)(bp + d * 8192 + rB0 + 16 * 128);
        acc[0][0] = __builtin_amdgcn_mfma_f32_16x16x32_bf16(a0, b0, acc[0][0], 0, 0, 0);
        acc[0][1] = __builtin_amdgcn_mfma_f32_16x16x32_bf16(a0, b1, acc[0][1], 0, 0, 0);
        acc[1][0] = __builtin_amdgcn_mfma_f32_16x16x32_bf16(a1, b0, acc[1][0], 0, 0, 0);
        acc[1][1] = __builtin_amdgcn_mfma_f32_16x16x32_bf16(a1, b1, acc[1][1], 0, 0, 0);
      }
      __builtin_amdgcn_s_setprio(0);
    };

    stage(0); stage(1);
    asm volatile("s_waitcnt vmcnt(5)" ::: "memory");   // stage(0) landed
    __builtin_amdgcn_s_barrier();

    for (int m = 0; m < 8; ++m) {
      if (m < 7) { stage(2 * m + 2); stage(2 * m + 3); }
      if (m < 7) asm volatile("s_waitcnt vmcnt(15)" ::: "memory");
      else       asm volatile("s_waitcnt vmcnt(5)" ::: "memory");
      mfma_iter(2 * m);
      if (m < 7) asm volatile("s_waitcnt vmcnt(10)" ::: "memory");
      else       asm volatile("s_waitcnt vmcnt(0)" ::: "memory");
      mfma_iter(2 * m + 1);
      __builtin_amdgcn_sched_barrier(0);
      __builtin_amdgcn_s_barrier();      // one barrier per 2 iterations
    }
    __syncthreads();   // last buf reads done; LDS reusable

    // ---- merge kh halves: kh0 -> aggS, kh1 -> aggS2 (no extra barrier) --
    {
      float (*dstp)[68] = (kh == 0) ? aggS : aggS2;
#pragma unroll
      for (int fr = 0; fr < 2; ++fr)
#pragma unroll
        for (int fc = 0; fc < 2; ++fc)
#pragma unroll
          for (int rr = 0; rr < 4; ++rr)
            dstp[wr * 32 + fr * 16 + g * 4 + rr][wc * 32 + fc * 16 + l15] = acc[fr][fc][rr];
    }
    __syncthreads();

    // ---- (aggS+aggS2) -> bf16 hi/lo planes (chunk-swizzled) ----
    {
      const int row = tid >> 3, c8 = tid & 7;
      const float* src  = &aggS[row][c8 * 8];
      const float* src2 = &aggS2[row][c8 * 8];
      ushort8_v H, L;
#pragma unroll
      for (int q = 0; q < 8; ++q) {
        float f = src[q] + src2[q];
        unsigned short hv = f2bf(f);
        H[q] = hv; L[q] = f2bf(f - bf2f(hv));
      }
      const int pos = (c8 ^ (row & 7)) << 4;
      *(ushort8_v*)(smem + AGGH + row * 128 + pos) = H;
      *(ushort8_v*)(smem + AGGL + row * 128 + pos) = L;
    }
    // ---- stage h_k -> hH/hL planes ----
    {
      const int cl = tid >> 3, ich = (tid & 7) * 8;
      size_t off = ((size_t)((k + 1) & 3) << 20) + (size_t)(c0 + cl) * NN + (i0 + ich);
      ushort8_v h8 = *(const ushort8_v*)(SThi + off);
      ushort8_v l8 = *(const ushort8_v*)(STlo + off);
#pragma unroll
      for (int q = 0; q < 8; ++q) {
        int i = ich + q;
        int byo = i * 128 + ((((cl >> 3) ^ (i & 7))) << 4) + (cl & 7) * 2;
        *(unsigned short*)(smem + HH_ + byo) = h8[q];
        *(unsigned short*)(smem + HL_ + byo) = l8[q];
      }
    }
    __syncthreads();

    // ---- MFMA mini-GEMM: pre = [agg|h](64x128) @ W^T-frags (K=128) ----
    const int mr = w & 3, nc = w >> 2;   // 4 row-frags x 2 col-pairs
    f32x4 pacc[2];
    pacc[0] = (f32x4){0.f, 0.f, 0.f, 0.f};
    pacc[1] = (f32x4){0.f, 0.f, 0.f, 0.f};
#pragma unroll
    for (int ks = 0; ks < 4; ++ks) {
      const int base = (ks < 2) ? AGGH : HH_;
      const int ks2 = ks & 1;
      const int cxa = ((ks2 * 4 + g) ^ (l15 & 7)) << 4;
      const char* ra = smem + base + (mr * 16 + l15) * 128 + cxa;
      short8_v aH = *(const short8_v*)ra;
      short8_v aL = *(const short8_v*)(ra + 8192);
#pragma unroll
      for (int fc = 0; fc < 2; ++fc) {
        const int n = (nc * 2 + fc) * 16 + l15;
        const int cxb = ((ks * 4 + g) ^ l15) << 4;
        short8_v bv = *(const short8_v*)(smem + WGT_L + n * 256 + cxb);
        pacc[fc] = __builtin_amdgcn_mfma_f32_16x16x32_bf16(aH, bv, pacc[fc], 0, 0, 0);
        pacc[fc] = __builtin_amdgcn_mfma_f32_16x16x32_bf16(aL, bv, pacc[fc], 0, 0, 0);
      }
    }
    // (no barrier: HT32 region does not overlap the planes read above)

    // ---- dx@Wx + bias, tanh; write ST ring + packed hT32 plane ----
    const int ksp = (k < 11) ? k : 10;
    float hn[2][4];
#pragma unroll
    for (int rr = 0; rr < 4; ++rr) {
      int iG = i0 + mr * 16 + g * 4 + rr;
      size_t cbase = ((size_t)(b * NN + iG) * NKNOTS + ksp) * 2;
      float dx0 = cb[cbase + 0], dx1 = cb[cbase + 1];
      if (k == 11) {   // frac = 1: der = b + 2c + 3d
        dx0 += 2.f * cc[cbase + 0] + 3.f * cd[cbase + 0];
        dx1 += 2.f * cc[cbase + 1] + 3.f * cd[cbase + 1];
      }
#pragma unroll
      for (int fc = 0; fc < 2; ++fc) {
        int hcol = (nc * 2 + fc) * 16 + l15;
        float pre = pacc[fc][rr] + dx0 * sWx[hcol] + dx1 * sWx[64 + hcol] + sdb[hcol];
        hn[fc][rr] = tanhf(pre);
      }
    }
#pragma unroll
    for (int fc = 0; fc < 2; ++fc) {
      int hcol = (nc * 2 + fc) * 16 + l15;
      int iG0 = i0 + mr * 16 + g * 4;
      size_t off2 = ((size_t)((k + 2) & 3) << 20) + (size_t)(c0 + hcol) * NN + iG0;
      ushort4_v H4, L4;
      uint4_v pk;
#pragma unroll
      for (int rr = 0; rr < 4; ++rr) {
        unsigned short hv = f2bf(hn[fc][rr]);
        unsigned short lv = f2bf(hn[fc][rr] - bf2f(hv));
        H4[rr] = hv; L4[rr] = lv;
        pk[rr] = ((unsigned int)hv << 16) | lv;
      }
      *(ushort4_v*)(SThi + off2) = H4;
      *(ushort4_v*)(STlo + off2) = L4;
      const int ci = mr * 4 + g;           // i-chunk (4 i's = 16B)
      *(uint4_v*)(smem + HT32 + hcol * 256 + ((ci ^ (hcol & 15)) << 4)) = pk;
    }
    // ---- signal-early: ST stores are L2-visible after vmcnt(0) drain ----
    asm volatile("s_waitcnt vmcnt(0)" ::: "memory");
    __syncthreads();                        // HT32 visible + stores drained
    if (tid == 0) atomicAdd(&syncc[b * 32 + k], 1u);

    // ---- reg head + Huber (h_new from hT32 plane) ----
    {
      const int ii = tid & 63, mg4 = (tid >> 6) * 4;
      float s0 = rb1[mg4], s1 = rb1[mg4 + 1], s2 = rb1[mg4 + 2], s3 = rb1[mg4 + 3];
#pragma unroll 8
      for (int h = 0; h < 64; ++h) {
        unsigned int v = *(const unsigned int*)(smem + HT32 + h * 256 +
                           ((((ii >> 2) ^ (h & 15))) << 4) + (ii & 3) * 4);
        float f = bf2f((unsigned short)(v >> 16)) + bf2f((unsigned short)(v & 0xffff));
        float4 wv = *(const float4*)(rW1 + h * 32 + mg4);
        s0 = fmaf(f, wv.x, s0); s1 = fmaf(f, wv.y, s1);
        s2 = fmaf(f, wv.z, s2); s3 = fmaf(f, wv.w, s3);
      }
      float4 r2v = *(const float4*)(rW2 + mg4);
      float rp = fmaxf(s0, 0.f) * r2v.x + fmaxf(s1, 0.f) * r2v.y +
                 fmaxf(s2, 0.f) * r2v.z + fmaxf(s3, 0.f) * r2v.w;
      float* redS = (float*)(smem + REDS);
      redS[(tid >> 6) * 64 + ii] = rp;
      __syncthreads();
      if (tid < 64) {
        float rv = rb2[0];
#pragma unroll
        for (int m = 0; m < 8; ++m) rv += redS[m * 64 + tid];
        int iG = i0 + tid;
        size_t tb = ((size_t)(b * NN + iG) * NKNOTS + ksp) * 2;
        float tgt = ca[tb];
        if (k == 11) tgt += cb[tb] + cc[tb] + cd[tb];   // frac=1: a+b+c+d
        float dv = rv - tgt;
        float ad = fabsf(dv);
        float hub = (ad < 1.f) ? 0.5f * dv * dv : (ad - 0.5f);
        hub += __shfl_down(hub, 32);
        hub += __shfl_down(hub, 16);
        hub += __shfl_down(hub, 8);
        hub += __shfl_down(hub, 4);
        hub += __shfl_down(hub, 2);
        hub += __shfl_down(hub, 1);
        if (tid == 0) atomicAdd(loss, hub);
      }
    }

    // ---- pred head (k == 11 only) ----
    if (k == 11) {
      __syncthreads();
      const int ii = tid & 63, mg4 = (tid >> 6) * 4;
      float s0 = pb1[mg4], s1 = pb1[mg4 + 1], s2 = pb1[mg4 + 2], s3 = pb1[mg4 + 3];
#pragma unroll 8
      for (int h = 0; h < 64; ++h) {
        unsigned int v = *(const unsigned int*)(smem + HT32 + h * 256 +
                           ((((ii >> 2) ^ (h & 15))) << 4) + (ii & 3) * 4);
        float f = bf2f((unsigned short)(v >> 16)) + bf2f((unsigned short)(v & 0xffff));
        float4 wv = *(const float4*)(pW1 + h * 32 + mg4);
        s0 = fmaf(f, wv.x, s0); s1 = fmaf(f, wv.y, s1);
        s2 = fmaf(f, wv.z, s2); s3 = fmaf(f, wv.w, s3);
      }
      float* pl1 = (float*)(smem + PL1);
      pl1[ii * 32 + mg4 + 0] = fmaxf(s0, 0.f);
      pl1[ii * 32 + mg4 + 1] = fmaxf(s1, 0.f);
      pl1[ii * 32 + mg4 + 2] = fmaxf(s2, 0.f);
      pl1[ii * 32 + mg4 + 3] = fmaxf(s3, 0.f);
      __syncthreads();
#pragma unroll
      for (int rep = 0; rep < 2; ++rep) {
        int idxp = tid + rep * 512;
        if (idxp < 768) {
          int i_ = idxp / 12, o = idxp % 12;
          float s = pb2[o];
#pragma unroll
          for (int m = 0; m < 32; ++m) s = fmaf(pl1[i_ * 32 + m], pW2[m * 12 + o], s);
          out[((size_t)b * NN + (i0 + i_)) * 12 + o] = s;
        }
      }
    }

    // ---- per-batch wait (16 arrivals, XCD-local) + L1-only invalidate ----
    // (no pre-spin barrier: spin only gates next-step staging, protected by
    //  the post-spin barrier; heads proceed concurrently with the spin)
    if (tid == 0) {
      unsigned int* ctr = &syncc[b * 32 + k];
      while (atomicAdd(ctr, 0u) < 16u) __builtin_amdgcn_s_sleep(1);
      asm volatile("buffer_inv sc0" ::: "memory");   // drop stale vector-L1
    }
    __syncthreads();
  }
}

__global__ void finalize_kernel(const float* __restrict__ loss, float* __restrict__ out)
{
  out[196608] = loss[0] * (1.0f / 196608.0f);
}

// -------------------------------------------------------------------------
extern "C" void kernel_launch(void* const* d_in, const int* in_sizes, int n_in,
                              void* d_out, int out_size, void* d_ws, size_t ws_size,
                              hipStream_t stream)
{
  const float* A     = (const float*)d_in[0];
  const float* delay = (const float*)d_in[1];
  const float* ca    = (const float*)d_in[2];
  const float* cb    = (const float*)d_in[3];
  const float* cc    = (const float*)d_in[4];
  const float* cd    = (const float*)d_in[5];
  const float* emb   = (const float*)d_in[6];
  const float* iW1   = (const float*)d_in[7];
  const float* ib1   = (const float*)d_in[8];
  const float* iW2   = (const float*)d_in[9];
  const float* ib2   = (const float*)d_in[10];
  const float* Wm    = (const float*)d_in[11];
  const float* Wsm   = (const float*)d_in[12];
  const float* Wx    = (const float*)d_in[13];
  const float* db    = (const float*)d_in[14];
  const float* rW1   = (const float*)d_in[15];
  const float* rb1   = (const float*)d_in[16];
  const float* rW2   = (const float*)d_in[17];
  const float* rb2   = (const float*)d_in[18];
  const float* pW1   = (const float*)d_in[19];
  const float* pb1   = (const float*)d_in[20];
  const float* pW2   = (const float*)d_in[21];
  const float* pb2   = (const float*)d_in[22];

  char* wsb = (char*)d_ws;
  float* out = (float*)d_out;
  unsigned short* Wpk  = (unsigned short*)(wsb + WPK_OFF);
  unsigned int*  M3g   = (unsigned int*)(wsb + M3_OFF);
  unsigned short* SThi = (unsigned short*)(wsb + STHI_OFF);
  unsigned short* STlo = (unsigned short*)(wsb + STLO_OFF);
  unsigned short* wgt  = (unsigned short*)(wsb + WGT_OFF);
  unsigned int* syncc  = (unsigned int*)(wsb + SYNC_OFF);
  float* loss          = (float*)(wsb + LOSS_OFF);
  float* Z             = (float*)(wsb + Z_OFF);
  float* dinv          = (float*)(wsb + DINV_OFF);

  hipMemsetAsync(syncc, 0, 2048 + 64, stream);   // sync counters + loss
  rowstats_kernel<<<NN, 256, 0, stream>>>(emb, A, Z, dinv);
  build_wt_kernel<<<256, 256, 0, stream>>>(emb, A, delay, Z, dinv, Wpk, M3g);
  init_s_kernel<<<288, 256, 0, stream>>>(ca, iW1, ib1, iW2, ib2,
                                         SThi, STlo, Wm, Wsm, wgt);
  scan_kernel<<<256, 512, 0, stream>>>(
      Wpk, M3g, SThi, STlo, wgt, syncc, Wx, db, cb, cc, cd, ca,
      rW1, rb1, rW2, rb2, pW1, pb1, pW2, pb2, out, loss);
  finalize_kernel<<<1, 1, 0, stream>>>(loss, out);
}